// Round 1
// baseline (1493.274 us; speedup 1.0000x reference)
//
#include <hip/hip_runtime.h>

// AttentionBasedNN: persistent mega-kernel version.
// VEC=1280, HID=128, B=4, S=256, fp32 (no fp32 MFMA on CDNA4 -> vector ALU).
//
// Round-5: all 26 dispatches fused into ONE persistent kernel (512 blocks x
// 256 threads, __launch_bounds__(256,2) -> 2 blocks/CU guaranteed resident:
// VGPR<=256, static LDS ~35KB <= 80KB). Dispatch boundaries replaced by a
// sense-reversing device-scope barrier (23 grid syncs). Per-phase math is
// bit-identical to the round-4 kernels. Layer-4 tail (scores4+pv4+lnhead)
// fused into a single 4-block phase (aw4/A4 live in LDS).

#define DEV __device__ __forceinline__

static constexpr int VEC = 1280;
static constexpr int HID = 128;
static constexpr int BB  = 4;
static constexpr int SS  = 256;
static constexpr int NPART = 8;           // split-K partials (QK and FC1)
static constexpr long QK_PS = 262144;     // QK partial stride (1024*256)
static constexpr long H_PS  = 131072;     // FC1 partial stride (1024*128)
static constexpr int NBLK  = 512;         // persistent grid: 2 blocks/CU
static constexpr int NSPLIT_NONE = 1 << 30;

struct Params {
  const float* X; const int* lys;
  const float* Wq[4]; const float* Wk[4]; const float* wv[4];
  const float* rW1[3]; const float* rb1[3]; const float* rW2[3]; const float* rb2[3];
  const float* hW1; const float* hb1; const float* hW2; const float* hb2;
  const float* hW3; const float* hb3;
  float* QKp; float* Qd; float* KT; float* attn; float* Yraw; float* Yb; float* Hp;
  float* buf0; float* buf1; float* out;
  unsigned* bar;   // bar[0]=count, bar[1]=generation
};

DEV float ftanh(float x) {
  float e = __expf(2.0f * x);
  return 1.0f - __fdividef(2.0f, e + 1.0f);
}

DEV float waveSum(float v) {
#pragma unroll
  for (int off = 32; off > 0; off >>= 1) v += __shfl_xor(v, off, 64);
  return v;
}
DEV float waveMax(float v) {
#pragma unroll
  for (int off = 32; off > 0; off >>= 1) v = fmaxf(v, __shfl_xor(v, off, 64));
  return v;
}
// blockDim.x == 256 (4 waves) everywhere these are used.
DEV float blockSum(float v, float* red) {
  v = waveSum(v);
  int tid = threadIdx.x;
  if ((tid & 63) == 0) red[tid >> 6] = v;
  __syncthreads();
  float r = (red[0] + red[1]) + (red[2] + red[3]);
  __syncthreads();
  return r;
}
DEV float blockMax(float v, float* red) {
  v = waveMax(v);
  int tid = threadIdx.x;
  if ((tid & 63) == 0) red[tid >> 6] = v;
  __syncthreads();
  float r = fmaxf(fmaxf(red[0], red[1]), fmaxf(red[2], red[3]));
  __syncthreads();
  return r;
}

// Grid-wide sense-reversing barrier. All 512 blocks are co-resident
// (launch_bounds occupancy math), so spinning is deadlock-free.
// Release on arrive (acq_rel fetch_add publishes this block's phase writes:
// syncthreads drains each wave's stores to L2, the agent-scope release
// writes L2 back to the coherence point). Acquire on depart invalidates
// L1/L2 so next-phase reads see other XCDs' writes.
DEV void gsync(unsigned* bar) {
  __syncthreads();
  if (threadIdx.x == 0) {
    unsigned g = __hip_atomic_load(bar + 1, __ATOMIC_RELAXED,
                                   __HIP_MEMORY_SCOPE_AGENT);
    unsigned a = __hip_atomic_fetch_add(bar, 1u, __ATOMIC_ACQ_REL,
                                        __HIP_MEMORY_SCOPE_AGENT);
    if (a == (unsigned)(NBLK - 1)) {
      __hip_atomic_store(bar, 0u, __ATOMIC_RELAXED, __HIP_MEMORY_SCOPE_AGENT);
      __hip_atomic_store(bar + 1, g + 1u, __ATOMIC_RELEASE,
                         __HIP_MEMORY_SCOPE_AGENT);
    } else {
      while (__hip_atomic_load(bar + 1, __ATOMIC_RELAXED,
                               __HIP_MEMORY_SCOPE_AGENT) == g)
        __builtin_amdgcn_s_sleep(4);
      __builtin_amdgcn_fence(__ATOMIC_ACQUIRE, "agent");
    }
  }
  __syncthreads();
}

// ---------------------------------------------------------------------------
// fp32 GEMM task, 64x64 tile, BK=16, 256 threads, 4x4 microtile, register
// double-buffered staging. Identical math to round-4 gemm_k; blockIdx
// replaced by explicit (n0, m0, z).
// MODE==0: plain.  MODE==1: z = K-split slice (kChunk each), C += z*sCb.
// MODE==2: z = batch; A += z*sAb, B += z*sBb, C/res += z*sCb.
// AFUSE: A element = relu(sum of NPART partials (stride aPart) + aBias[k]).
// Dual-B: output col n < nSplitB reads B0, else B1 at col n-nSplitB.
// ---------------------------------------------------------------------------
template <int MODE, bool AFUSE, bool OBIAS, bool ORES>
DEV void gemm_task(int n0, int m0, int z,
                   const float* __restrict__ A, long sAb, long aPart,
                   const float* __restrict__ B0, const float* __restrict__ B1,
                   int nSplitB, long sBb, int ldB,
                   float* __restrict__ C, long sCb,
                   const float* __restrict__ aBias,
                   const float* __restrict__ oBias,
                   const float* __restrict__ res,
                   int N, int K, int kChunk) {
  __shared__ float As[16][68];  // [k][m]
  __shared__ float Bs[16][68];  // [k][n]

  const float* Ab = A + (MODE == 2 ? (long)z * sAb : 0L);
  float*       Cb = C + (MODE >= 1 ? (long)z * sCb : 0L);
  const float* resz = ORES ? (res + (MODE == 2 ? (long)z * sCb : 0L)) : nullptr;
  const float* Bsel;
  int nb;
  if (n0 < nSplitB) { Bsel = B0; nb = n0; } else { Bsel = B1; nb = n0 - nSplitB; }
  if (MODE == 2) Bsel += (long)z * sBb;

  const int kBeg = (MODE == 1) ? z * kChunk : 0;
  const int kEnd = (MODE == 1) ? kBeg + kChunk : K;

  const int tid = threadIdx.x;
  const int tx = tid & 15, ty = tid >> 4;
  const int ar = tid >> 2, ac = (tid & 3) << 2;   // A: row 0..63, k {0,4,8,12}
  const int br = tid >> 4, bc = (tid & 15) << 2;  // B: k-row 0..15, col 0..60

  auto loadA = [&](int kt) -> float4 {
    const size_t aoff = (size_t)(m0 + ar) * K + kt + ac;
    if (AFUSE) {
      float4 s = *(const float4*)(Ab + aoff);
#pragma unroll
      for (int p = 1; p < NPART; ++p) {
        const float4 t = *(const float4*)(Ab + (long)p * aPart + aoff);
        s.x += t.x; s.y += t.y; s.z += t.z; s.w += t.w;
      }
      const float4 bz = *(const float4*)(aBias + kt + ac);
      s.x = fmaxf(s.x + bz.x, 0.0f);
      s.y = fmaxf(s.y + bz.y, 0.0f);
      s.z = fmaxf(s.z + bz.z, 0.0f);
      s.w = fmaxf(s.w + bz.w, 0.0f);
      return s;
    }
    return *(const float4*)(Ab + aoff);
  };
  auto loadB = [&](int kt) -> float4 {
    return *(const float4*)(Bsel + (size_t)(kt + br) * ldB + nb + bc);
  };

  float acc[4][4] = {};
  float4 a4 = loadA(kBeg);
  float4 b4 = loadB(kBeg);

  for (int kt = kBeg; kt < kEnd; kt += 16) {
    __syncthreads();
    As[ac + 0][ar] = a4.x;
    As[ac + 1][ar] = a4.y;
    As[ac + 2][ar] = a4.z;
    As[ac + 3][ar] = a4.w;
    *(float4*)&Bs[br][bc] = b4;
    __syncthreads();
    if (kt + 16 < kEnd) {  // prefetch next tile under compute
      a4 = loadA(kt + 16);
      b4 = loadB(kt + 16);
    }
#pragma unroll
    for (int kk = 0; kk < 16; ++kk) {
      const float4 av = *(const float4*)&As[kk][ty << 2];
      const float4 bv = *(const float4*)&Bs[kk][tx << 2];
      const float a[4] = {av.x, av.y, av.z, av.w};
      const float b[4] = {bv.x, bv.y, bv.z, bv.w};
#pragma unroll
      for (int i = 0; i < 4; ++i)
#pragma unroll
        for (int j = 0; j < 4; ++j) acc[i][j] = fmaf(a[i], b[j], acc[i][j]);
    }
  }

#pragma unroll
  for (int i = 0; i < 4; ++i) {
    const int m = m0 + (ty << 2) + i;
#pragma unroll
    for (int j = 0; j < 4; ++j) {
      const int n = n0 + (tx << 2) + j;
      float v = acc[i][j];
      if (OBIAS) v += oBias[n];
      if (ORES) v += resz[(size_t)m * N + n];
      Cb[(size_t)m * N + n] = v;
    }
  }
}

// Reduce NPART QK partials row r (cols 0..127=Q, 128..255=K) into Qd + KT.
DEV void qksum_task(int r, const float* __restrict__ QKp,
                    float* __restrict__ Qd, float* __restrict__ KT) {
  const int tid = threadIdx.x;
  const int b = r >> 8, j = r & 255;
  const size_t off = (size_t)r * 256 + tid;
  float v = 0.0f;
#pragma unroll
  for (int p = 0; p < NPART; ++p) v += QKp[(long)p * QK_PS + off];
  if (tid < 128) {
    Qd[(size_t)r * 128 + tid] = v;
  } else {
    KT[(size_t)b * 32768 + (size_t)(tid - 128) * 256 + j] = v;
  }
}

// Scores + softmax for 2 q-rows. t in [0,512): b = t>>7, i0 = (t&127)*2.
DEV void scores_task(int t, const float* __restrict__ Qd,
                     const float* __restrict__ KT,
                     const float* __restrict__ wv,
                     float* __restrict__ attn) {
  const int b = t >> 7, i0 = (t & 127) << 1, tid = threadIdx.x;
  __shared__ float qs[2][128], wvs[128], red[4];
  {
    const int rr = tid >> 7, h = tid & 127;
    qs[rr][h] = Qd[(size_t)(b * 256 + i0 + rr) * 128 + h];
  }
  if (tid < 128) wvs[tid] = wv[tid];
  __syncthreads();

  const float* KTb = KT + (size_t)b * 32768 + tid;
  float s0 = 0.0f, s1 = 0.0f;
#pragma unroll 4
  for (int h = 0; h < 128; h += 4) {
    const float k0 = KTb[(h + 0) * 256];
    const float k1 = KTb[(h + 1) * 256];
    const float k2 = KTb[(h + 2) * 256];
    const float k3 = KTb[(h + 3) * 256];
    const float w0 = wvs[h], w1 = wvs[h + 1], w2 = wvs[h + 2], w3 = wvs[h + 3];
    s0 += w0 * ftanh(qs[0][h] + k0) + w1 * ftanh(qs[0][h + 1] + k1) +
          w2 * ftanh(qs[0][h + 2] + k2) + w3 * ftanh(qs[0][h + 3] + k3);
    s1 += w0 * ftanh(qs[1][h] + k0) + w1 * ftanh(qs[1][h + 1] + k1) +
          w2 * ftanh(qs[1][h + 2] + k2) + w3 * ftanh(qs[1][h + 3] + k3);
  }
  {
    const float mx = blockMax(s0, red);
    const float e = __expf(s0 - mx);
    const float tot = blockSum(e, red);
    attn[(size_t)(b * 256 + i0) * 256 + tid] = e / tot;
  }
  {
    const float mx = blockMax(s1, red);
    const float e = __expf(s1 - mx);
    const float tot = blockSum(e, red);
    attn[(size_t)(b * 256 + i0 + 1) * 256 + tid] = e / tot;
  }
}

// LayerNorm of row r of A -> Y.
DEV void ln_task(int r, const float* __restrict__ A, float* __restrict__ Y) {
  __shared__ float red[4];
  const int tid = threadIdx.x;
  const float* a = A + (size_t)r * VEC;
  float v[5];
  float sum = 0.0f;
#pragma unroll
  for (int k = 0; k < 5; ++k) {
    v[k] = a[tid + k * 256];
    sum += v[k];
  }
  sum = blockSum(sum, red);
  const float m = sum * (1.0f / VEC);
  float sq = 0.0f;
#pragma unroll
  for (int k = 0; k < 5; ++k) {
    const float dl = v[k] - m;
    sq += dl * dl;
  }
  sq = blockSum(sq, red);
  const float rstd = rsqrtf(sq * (1.0f / VEC) + 1e-5f);
  float* y = Y + (size_t)r * VEC;
#pragma unroll
  for (int k = 0; k < 5; ++k) y[tid + k * 256] = (v[k] - m) * rstd;
}

// Fused layer-4 tail for batch b: scores4 + pv4 + LN + head, all in-block
// (aw4 and the attended row live in LDS/registers; no grid syncs needed).
DEV void tail_task(int b, const Params& p) {
  __shared__ float qs[128], wvs[128], red[4], aws[256];
  __shared__ float xrow[1280], partial[256];
  __shared__ float h1s[32], h2s[12];
  const int tid = threadIdx.x;
  const int lp = p.lys[0];
  const float* X3 = p.buf0;

  if (tid < 128) {
    qs[tid] = p.Qd[(size_t)(b * 256 + lp) * 128 + tid];
    wvs[tid] = p.wv[3][tid];
  }
  __syncthreads();
  const float* KTb = p.KT + (size_t)b * 32768 + tid;
  float s = 0.0f;
#pragma unroll 4
  for (int h = 0; h < 128; h += 4) {
    s += wvs[h + 0] * ftanh(qs[h + 0] + KTb[(h + 0) * 256]);
    s += wvs[h + 1] * ftanh(qs[h + 1] + KTb[(h + 1) * 256]);
    s += wvs[h + 2] * ftanh(qs[h + 2] + KTb[(h + 2) * 256]);
    s += wvs[h + 3] * ftanh(qs[h + 3] + KTb[(h + 3) * 256]);
  }
  const float mx = blockMax(s, red);
  const float e = __expf(s - mx);
  const float tot = blockSum(e, red);
  aws[tid] = e / tot;
  __syncthreads();

  // PV: 5 cols per thread (coalesced rows of X3[b]).
  const float* Xb = X3 + (size_t)b * SS * VEC;
  float v[5] = {};
#pragma unroll 2
  for (int j = 0; j < 256; ++j) {
    const float aw = aws[j];
    const float* xr = Xb + (size_t)j * VEC + tid;
#pragma unroll
    for (int k = 0; k < 5; ++k) v[k] = fmaf(aw, xr[k * 256], v[k]);
  }
#pragma unroll
  for (int k = 0; k < 5; ++k) v[k] += Xb[(size_t)lp * VEC + tid + k * 256];

  // LN over the 1280-wide attended row.
  float sum = (v[0] + v[1]) + (v[2] + v[3]) + v[4];
  sum = blockSum(sum, red);
  const float m = sum * (1.0f / VEC);
  float sq = 0.0f;
#pragma unroll
  for (int k = 0; k < 5; ++k) {
    const float dl = v[k] - m;
    sq += dl * dl;
  }
  sq = blockSum(sq, red);
  const float rstd = rsqrtf(sq * (1.0f / VEC) + 1e-5f);
#pragma unroll
  for (int k = 0; k < 5; ++k) xrow[tid + k * 256] = (v[k] - m) * rstd;
  __syncthreads();

  // Head: 1280 -> 32 (relu) -> 12 (relu) -> 2.
  {
    const int n = tid & 31, sl = tid >> 5;
    float pacc = 0.0f;
    for (int k = sl * 160; k < sl * 160 + 160; ++k)
      pacc = fmaf(xrow[k], p.hW1[(size_t)k * 32 + n], pacc);
    partial[tid] = pacc;
  }
  __syncthreads();
  if (tid < 32) {
    float t2 = 0.0f;
#pragma unroll
    for (int s2 = 0; s2 < 8; ++s2) t2 += partial[s2 * 32 + tid];
    h1s[tid] = fmaxf(t2 + p.hb1[tid], 0.0f);
  }
  __syncthreads();
  if (tid < 12) {
    float t2 = 0.0f;
#pragma unroll
    for (int k = 0; k < 32; ++k) t2 = fmaf(h1s[k], p.hW2[k * 12 + tid], t2);
    h2s[tid] = fmaxf(t2 + p.hb2[tid], 0.0f);
  }
  __syncthreads();
  if (tid < 2) {
    float t2 = 0.0f;
#pragma unroll
    for (int k = 0; k < 12; ++k) t2 = fmaf(h2s[k], p.hW3[k * 2 + tid], t2);
    p.out[b * 2 + tid] = t2 + p.hb3[tid];
  }
}

// ---------------------------------------------------------------------------
// The persistent kernel. 512 blocks x 256 threads; __launch_bounds__(256,2)
// = 2 waves/SIMD -> 2 blocks/CU -> all 512 blocks co-resident on 256 CUs
// (VGPR capped at 256, static LDS ~35 KB <= 80 KB/block).
// ---------------------------------------------------------------------------
__global__ __launch_bounds__(256, 2) void mega_k(Params p) {
  const int bid = blockIdx.x;
  const float* Pin[4]  = {p.X, p.buf0, p.buf1, p.buf0};
  float*       Pout[3] = {p.buf0, p.buf1, p.buf0};

  for (int l = 0; l < 4; ++l) {
    const float* Xin = Pin[l];
    {  // QK projection: QKp[z] = Xin @ [Wq|Wk], K-slice z. 512 tasks.
      const int x = bid & 3, y = (bid >> 2) & 15, z = bid >> 6;
      gemm_task<1, false, false, false>(x * 64, y * 64, z, Xin, 0L, 0L,
          p.Wq[l], p.Wk[l], HID, 0L, HID, p.QKp, QK_PS,
          nullptr, nullptr, nullptr, 2 * HID, VEC, 160);
    }
    gsync(p.bar);
    // Reduce partials -> dense Qd + transposed KT. 1024 rows / 512 blocks.
    qksum_task(bid, p.QKp, p.Qd, p.KT);
    qksum_task(bid + NBLK, p.QKp, p.Qd, p.KT);
    gsync(p.bar);
    if (l == 3) break;
    // attn = softmax(wv . tanh(q_i + k_j)). 512 tasks.
    scores_task(bid, p.Qd, p.KT, p.wv[l], p.attn);
    gsync(p.bar);
    // Yraw = attn @ Xin + Xin (batched). 320 tasks.
    if (bid < 320) {
      const int x = bid % 20, y = (bid / 20) & 3, zb = bid / 80;
      gemm_task<2, false, false, true>(x * 64, y * 64, zb, p.attn,
          (long)SS * SS, 0L, Xin, Xin, NSPLIT_NONE, (long)SS * VEC, VEC,
          p.Yraw, (long)SS * VEC, nullptr, nullptr, Xin, VEC, SS, 0);
    }
    gsync(p.bar);
    // Yb = LN(Yraw). 1024 rows / 512 blocks.
    ln_task(bid, p.Yraw, p.Yb);
    ln_task(bid + NBLK, p.Yraw, p.Yb);
    gsync(p.bar);
    // Hp[z] = Yb @ rW1, K-slice z. 256 tasks.
    if (bid < 256) {
      const int x = bid & 1, y = (bid >> 1) & 15, z = bid >> 5;
      gemm_task<1, false, false, false>(x * 64, y * 64, z, p.Yb, 0L, 0L,
          p.rW1[l], p.rW1[l], NSPLIT_NONE, 0L, HID, p.Hp, H_PS,
          nullptr, nullptr, nullptr, HID, VEC, 160);
    }
    gsync(p.bar);
    // Xout = relu(sum(Hp)+b1) @ rW2 + b2 + Yb. 320 tasks.
    if (bid < 320) {
      const int x = bid % 20, y = bid / 20;
      gemm_task<0, true, true, true>(x * 64, y * 64, 0, p.Hp, 0L, H_PS,
          p.rW2[l], p.rW2[l], NSPLIT_NONE, 0L, VEC, Pout[l], 0L,
          p.rb1[l], p.rb2[l], p.Yb, VEC, HID, 0);
    }
    gsync(p.bar);
  }
  // Layer-4 tail: one block per batch, fully fused.
  if (bid < BB) tail_task(bid, p);
}

__global__ void initbar_k(unsigned* __restrict__ bar) {
  __hip_atomic_store(bar + 0, 0u, __ATOMIC_RELAXED, __HIP_MEMORY_SCOPE_SYSTEM);
  __hip_atomic_store(bar + 1, 0u, __ATOMIC_RELAXED, __HIP_MEMORY_SCOPE_SYSTEM);
}

// ---------------------------------------------------------------------------
extern "C" void kernel_launch(void* const* d_in, const int* in_sizes, int n_in,
                              void* d_out, int out_size, void* d_ws, size_t ws_size,
                              hipStream_t stream) {
  Params p;
  p.X   = (const float*)d_in[0];
  p.lys = (const int*)d_in[1];
  p.Wq[0] = (const float*)d_in[2];  p.Wk[0] = (const float*)d_in[3];  p.wv[0] = (const float*)d_in[4];
  p.Wq[1] = (const float*)d_in[5];  p.Wk[1] = (const float*)d_in[6];  p.wv[1] = (const float*)d_in[7];
  p.Wq[2] = (const float*)d_in[8];  p.Wk[2] = (const float*)d_in[9];  p.wv[2] = (const float*)d_in[10];
  p.Wq[3] = (const float*)d_in[11]; p.Wk[3] = (const float*)d_in[12]; p.wv[3] = (const float*)d_in[13];
  p.rW1[0] = (const float*)d_in[14]; p.rb1[0] = (const float*)d_in[15];
  p.rW2[0] = (const float*)d_in[16]; p.rb2[0] = (const float*)d_in[17];
  p.rW1[1] = (const float*)d_in[18]; p.rb1[1] = (const float*)d_in[19];
  p.rW2[1] = (const float*)d_in[20]; p.rb2[1] = (const float*)d_in[21];
  p.rW1[2] = (const float*)d_in[22]; p.rb1[2] = (const float*)d_in[23];
  p.rW2[2] = (const float*)d_in[24]; p.rb2[2] = (const float*)d_in[25];
  p.hW1 = (const float*)d_in[26]; p.hb1 = (const float*)d_in[27];
  p.hW2 = (const float*)d_in[28]; p.hb2 = (const float*)d_in[29];
  p.hW3 = (const float*)d_in[30]; p.hb3 = (const float*)d_in[31];
  p.out = (float*)d_out;

  // Workspace layout (floats), ~36 MB (same as round-4) + barrier words.
  float* ws = (float*)d_ws;
  p.QKp  = ws;                               // NPART x 262144
  p.Qd   = p.QKp + (long)NPART * QK_PS;      // 1024*128
  p.KT   = p.Qd + 131072;                    // 4*128*256
  p.attn = p.KT + 131072;                    // 1024*256
  p.Yraw = p.attn + 262144;                  // 1024*1280
  p.Yb   = p.Yraw + 1310720;                 // 1024*1280
  p.Hp   = p.Yb + 1310720;                   // NPART x 131072
  p.buf0 = p.Hp + (long)NPART * H_PS;        // 1024*1280
  p.buf1 = p.buf0 + 1310720;                 // 1024*1280
  float* aw4 = p.buf1 + 1310720;             // (unused now) 4*256
  float* A4  = aw4 + 1024;                   // (unused now) 4*1280
  p.bar = (unsigned*)(A4 + 4 * VEC);         // 2 x u32 barrier state

  initbar_k<<<dim3(1), dim3(1), 0, stream>>>(p.bar);
  mega_k<<<dim3(NBLK), dim3(256), 0, stream>>>(p);
}

// Round 2
// 562.284 us; speedup vs baseline: 2.6557x; 2.6557x over previous
//
#include <hip/hip_runtime.h>

// AttentionBasedNN: persistent mega-kernel, round-6.
// VEC=1280, HID=128, B=4, S=256, fp32 (no fp32 MFMA on CDNA4 -> vector ALU).
//
// Round-5 post-mortem: 23 grid syncs at ~52us each -- agent-scope acq_rel
// fences emit buffer_wbl2/buffer_inv L2 tag-walks on EVERY block (64 walks
// serialized per XCD per barrier) and the repeated invalidates thrash L2
// refill (FETCH 200MB @ 240GB/s, VALUBusy 7.5%).
//
// Round-6 fix: make the barrier fence-free. ALL intermediate-buffer traffic
// uses relaxed agent-scope atomics (sc0 sc1: bypass L1+L2, served by shared
// L3, vmcnt-tracked so prefetch pipelining survives). Weights/inputs remain
// normally cached (read-only -> never stale -> keep L2/L1 reuse for GEMM
// B-operands). With no dirty/stale L2 possible, the grid barrier is just
// __syncthreads (drains vmcnt) + monotonic fence-free tree counters.
// Phase math is bit-identical to round-4/5.

#define DEV __device__ __forceinline__

static constexpr int VEC = 1280;
static constexpr int HID = 128;
static constexpr int BB  = 4;
static constexpr int SS  = 256;
static constexpr int NPART = 8;           // split-K partials (QK and FC1)
static constexpr long QK_PS = 262144;     // QK partial stride (1024*256)
static constexpr long H_PS  = 131072;     // FC1 partial stride (1024*128)
static constexpr int NBLK  = 512;         // persistent grid: 2 blocks/CU
static constexpr int NSPLIT_NONE = 1 << 30;

struct Params {
  const float* X; const int* lys;
  const float* Wq[4]; const float* Wk[4]; const float* wv[4];
  const float* rW1[3]; const float* rb1[3]; const float* rW2[3]; const float* rb2[3];
  const float* hW1; const float* hb1; const float* hW2; const float* hb2;
  const float* hW3; const float* hb3;
  float* QKp; float* Qd; float* KT; float* attn; float* Yraw; float* Yb; float* Hp;
  float* buf0; float* buf1; float* out;
  unsigned* bar;   // [0..255] group counters (stride 32), [256] root, [288] gen
};

// ---- cache-bypass (coherence-point) accessors for intermediates -----------
// Relaxed agent-scope atomics compile to global_load/store with sc0 sc1:
// bypass non-coherent L1/L2, land in / read from the shared L3. Normal
// vmcnt tracking, no fences ever needed.
DEV float ldcc(const float* p) {
  unsigned u = __hip_atomic_load((unsigned*)p, __ATOMIC_RELAXED,
                                 __HIP_MEMORY_SCOPE_AGENT);
  union { unsigned u; float f; } c; c.u = u; return c.f;
}
DEV float2 ldcc2(const float* p) {
  unsigned long long u = __hip_atomic_load((unsigned long long*)p,
                                           __ATOMIC_RELAXED,
                                           __HIP_MEMORY_SCOPE_AGENT);
  union { unsigned long long u; float2 f; } c; c.u = u; return c.f;
}
DEV float4 ldcc4(const float* p) {
  float2 a = ldcc2(p), b = ldcc2(p + 2);
  return make_float4(a.x, a.y, b.x, b.y);
}
DEV void stcc(float* p, float v) {
  union { float f; unsigned u; } c; c.f = v;
  __hip_atomic_store((unsigned*)p, c.u, __ATOMIC_RELAXED,
                     __HIP_MEMORY_SCOPE_AGENT);
}
DEV void stcc2(float* p, float a, float b) {
  union { float2 f; unsigned long long u; } c; c.f = make_float2(a, b);
  __hip_atomic_store((unsigned long long*)p, c.u, __ATOMIC_RELAXED,
                     __HIP_MEMORY_SCOPE_AGENT);
}

DEV float ftanh(float x) {
  float e = __expf(2.0f * x);
  return 1.0f - __fdividef(2.0f, e + 1.0f);
}

DEV float waveSum(float v) {
#pragma unroll
  for (int off = 32; off > 0; off >>= 1) v += __shfl_xor(v, off, 64);
  return v;
}
DEV float waveMax(float v) {
#pragma unroll
  for (int off = 32; off > 0; off >>= 1) v = fmaxf(v, __shfl_xor(v, off, 64));
  return v;
}
// blockDim.x == 256 (4 waves) everywhere these are used.
DEV float blockSum(float v, float* red) {
  v = waveSum(v);
  int tid = threadIdx.x;
  if ((tid & 63) == 0) red[tid >> 6] = v;
  __syncthreads();
  float r = (red[0] + red[1]) + (red[2] + red[3]);
  __syncthreads();
  return r;
}
DEV float blockMax(float v, float* red) {
  v = waveMax(v);
  int tid = threadIdx.x;
  if ((tid & 63) == 0) red[tid >> 6] = v;
  __syncthreads();
  float r = fmaxf(fmaxf(red[0], red[1]), fmaxf(red[2], red[3]));
  __syncthreads();
  return r;
}

// Fence-free grid barrier. Monotonic counters (no resets, no WAR):
// 8 group counters (64 blocks each, 128B apart), a root, a generation word.
// All data written before the barrier used bypass stores already drained to
// the coherence point by the pre-s_barrier vmcnt(0); no cache maintenance
// is required because no intermediate data lives in L1/L2.
DEV void gsync(unsigned* bar, unsigned target) {
  __syncthreads();  // compiler emits s_waitcnt vmcnt(0) ... before s_barrier
  if (threadIdx.x == 0) {
    asm volatile("s_waitcnt vmcnt(0)" ::: "memory");
    unsigned* grp  = bar + ((blockIdx.x >> 6) << 5);
    unsigned* root = bar + 256;
    unsigned* gen  = bar + 288;
    unsigned c = __hip_atomic_fetch_add(grp, 1u, __ATOMIC_RELAXED,
                                        __HIP_MEMORY_SCOPE_AGENT);
    if (c + 1u == target * 64u) {
      unsigned r = __hip_atomic_fetch_add(root, 1u, __ATOMIC_RELAXED,
                                          __HIP_MEMORY_SCOPE_AGENT);
      if (r + 1u == target * 8u) {
        __hip_atomic_store(gen, target, __ATOMIC_RELAXED,
                           __HIP_MEMORY_SCOPE_AGENT);
      }
    }
    while (__hip_atomic_load(gen, __ATOMIC_RELAXED,
                             __HIP_MEMORY_SCOPE_AGENT) < target)
      __builtin_amdgcn_s_sleep(8);
  }
  __syncthreads();
}

// ---------------------------------------------------------------------------
// fp32 GEMM task, 64x64 tile, BK=16, 256 threads, 4x4 microtile, register
// double-buffered staging. Identical math to round-4/5.
// MODE==0: plain.  MODE==1: z = K-split slice (kChunk each), C += z*sCb.
// MODE==2: z = batch; A += z*sAb, B += z*sBb, C/res += z*sCb.
// AFUSE: A element = relu(sum of NPART partials (stride aPart) + aBias[k]).
// ACC/BCC/RCC: that operand is an intermediate -> cache-bypass access.
// C-stores always bypass (all outputs are intermediates).
// ---------------------------------------------------------------------------
template <int MODE, bool AFUSE, bool OBIAS, bool ORES,
          bool ACC, bool BCC, bool RCC>
DEV void gemm_task(int n0, int m0, int z,
                   const float* __restrict__ A, long sAb, long aPart,
                   const float* __restrict__ B0, const float* __restrict__ B1,
                   int nSplitB, long sBb, int ldB,
                   float* __restrict__ C, long sCb,
                   const float* __restrict__ aBias,
                   const float* __restrict__ oBias,
                   const float* __restrict__ res,
                   int N, int K, int kChunk) {
  __shared__ float As[16][68];  // [k][m]
  __shared__ float Bs[16][68];  // [k][n]

  const float* Ab = A + (MODE == 2 ? (long)z * sAb : 0L);
  float*       Cb = C + (MODE >= 1 ? (long)z * sCb : 0L);
  const float* resz = ORES ? (res + (MODE == 2 ? (long)z * sCb : 0L)) : nullptr;
  const float* Bsel;
  int nb;
  if (n0 < nSplitB) { Bsel = B0; nb = n0; } else { Bsel = B1; nb = n0 - nSplitB; }
  if (MODE == 2) Bsel += (long)z * sBb;

  const int kBeg = (MODE == 1) ? z * kChunk : 0;
  const int kEnd = (MODE == 1) ? kBeg + kChunk : K;

  const int tid = threadIdx.x;
  const int tx = tid & 15, ty = tid >> 4;
  const int ar = tid >> 2, ac = (tid & 3) << 2;   // A: row 0..63, k {0,4,8,12}
  const int br = tid >> 4, bc = (tid & 15) << 2;  // B: k-row 0..15, col 0..60

  auto loadA = [&](int kt) -> float4 {
    const size_t aoff = (size_t)(m0 + ar) * K + kt + ac;
    if (AFUSE) {
      float4 s = ldcc4(Ab + aoff);
#pragma unroll
      for (int p = 1; p < NPART; ++p) {
        const float4 t = ldcc4(Ab + (long)p * aPart + aoff);
        s.x += t.x; s.y += t.y; s.z += t.z; s.w += t.w;
      }
      const float4 bz = *(const float4*)(aBias + kt + ac);
      s.x = fmaxf(s.x + bz.x, 0.0f);
      s.y = fmaxf(s.y + bz.y, 0.0f);
      s.z = fmaxf(s.z + bz.z, 0.0f);
      s.w = fmaxf(s.w + bz.w, 0.0f);
      return s;
    }
    if (ACC) return ldcc4(Ab + aoff);
    return *(const float4*)(Ab + aoff);
  };
  auto loadB = [&](int kt) -> float4 {
    const float* bp = Bsel + (size_t)(kt + br) * ldB + nb + bc;
    if (BCC) return ldcc4(bp);
    return *(const float4*)bp;
  };

  float acc[4][4] = {};
  float4 a4 = loadA(kBeg);
  float4 b4 = loadB(kBeg);

  for (int kt = kBeg; kt < kEnd; kt += 16) {
    __syncthreads();
    As[ac + 0][ar] = a4.x;
    As[ac + 1][ar] = a4.y;
    As[ac + 2][ar] = a4.z;
    As[ac + 3][ar] = a4.w;
    *(float4*)&Bs[br][bc] = b4;
    __syncthreads();
    if (kt + 16 < kEnd) {  // prefetch next tile under compute
      a4 = loadA(kt + 16);
      b4 = loadB(kt + 16);
    }
#pragma unroll
    for (int kk = 0; kk < 16; ++kk) {
      const float4 av = *(const float4*)&As[kk][ty << 2];
      const float4 bv = *(const float4*)&Bs[kk][tx << 2];
      const float a[4] = {av.x, av.y, av.z, av.w};
      const float b[4] = {bv.x, bv.y, bv.z, bv.w};
#pragma unroll
      for (int i = 0; i < 4; ++i)
#pragma unroll
        for (int j = 0; j < 4; ++j) acc[i][j] = fmaf(a[i], b[j], acc[i][j]);
    }
  }

#pragma unroll
  for (int i = 0; i < 4; ++i) {
    const int m = m0 + (ty << 2) + i;
    const int n = n0 + (tx << 2);
    float o[4] = {acc[i][0], acc[i][1], acc[i][2], acc[i][3]};
    if (OBIAS) {
#pragma unroll
      for (int j = 0; j < 4; ++j) o[j] += oBias[n + j];
    }
    if (ORES) {
      const float* rp = resz + (size_t)m * N + n;
      const float4 r4 = RCC ? ldcc4(rp) : *(const float4*)rp;
      o[0] += r4.x; o[1] += r4.y; o[2] += r4.z; o[3] += r4.w;
    }
    stcc2(&Cb[(size_t)m * N + n], o[0], o[1]);
    stcc2(&Cb[(size_t)m * N + n + 2], o[2], o[3]);
  }
}

// Reduce NPART QK partials row r (cols 0..127=Q, 128..255=K) into Qd + KT.
DEV void qksum_task(int r, const float* __restrict__ QKp,
                    float* __restrict__ Qd, float* __restrict__ KT) {
  const int tid = threadIdx.x;
  const int b = r >> 8, j = r & 255;
  const size_t off = (size_t)r * 256 + tid;
  float v = 0.0f;
#pragma unroll
  for (int p = 0; p < NPART; ++p) v += ldcc(QKp + (long)p * QK_PS + off);
  if (tid < 128) {
    stcc(Qd + (size_t)r * 128 + tid, v);
  } else {
    stcc(KT + (size_t)b * 32768 + (size_t)(tid - 128) * 256 + j, v);
  }
}

// Scores + softmax for 2 q-rows. t in [0,512): b = t>>7, i0 = (t&127)*2.
DEV void scores_task(int t, const float* __restrict__ Qd,
                     const float* __restrict__ KT,
                     const float* __restrict__ wv,
                     float* __restrict__ attn) {
  const int b = t >> 7, i0 = (t & 127) << 1, tid = threadIdx.x;
  __shared__ float qs[2][128], wvs[128], red[4];
  {
    const int rr = tid >> 7, h = tid & 127;
    qs[rr][h] = ldcc(Qd + (size_t)(b * 256 + i0 + rr) * 128 + h);
  }
  if (tid < 128) wvs[tid] = wv[tid];
  __syncthreads();

  const float* KTb = KT + (size_t)b * 32768 + tid;
  float s0 = 0.0f, s1 = 0.0f;
#pragma unroll 4
  for (int h = 0; h < 128; h += 4) {
    const float k0 = ldcc(KTb + (h + 0) * 256);
    const float k1 = ldcc(KTb + (h + 1) * 256);
    const float k2 = ldcc(KTb + (h + 2) * 256);
    const float k3 = ldcc(KTb + (h + 3) * 256);
    const float w0 = wvs[h], w1 = wvs[h + 1], w2 = wvs[h + 2], w3 = wvs[h + 3];
    s0 += w0 * ftanh(qs[0][h] + k0) + w1 * ftanh(qs[0][h + 1] + k1) +
          w2 * ftanh(qs[0][h + 2] + k2) + w3 * ftanh(qs[0][h + 3] + k3);
    s1 += w0 * ftanh(qs[1][h] + k0) + w1 * ftanh(qs[1][h + 1] + k1) +
          w2 * ftanh(qs[1][h + 2] + k2) + w3 * ftanh(qs[1][h + 3] + k3);
  }
  {
    const float mx = blockMax(s0, red);
    const float e = __expf(s0 - mx);
    const float tot = blockSum(e, red);
    stcc(attn + (size_t)(b * 256 + i0) * 256 + tid, e / tot);
  }
  {
    const float mx = blockMax(s1, red);
    const float e = __expf(s1 - mx);
    const float tot = blockSum(e, red);
    stcc(attn + (size_t)(b * 256 + i0 + 1) * 256 + tid, e / tot);
  }
}

// LayerNorm of row r of A -> Y.
DEV void ln_task(int r, const float* __restrict__ A, float* __restrict__ Y) {
  __shared__ float red[4];
  const int tid = threadIdx.x;
  const float* a = A + (size_t)r * VEC;
  float v[5];
  float sum = 0.0f;
#pragma unroll
  for (int k = 0; k < 5; ++k) {
    v[k] = ldcc(a + tid + k * 256);
    sum += v[k];
  }
  sum = blockSum(sum, red);
  const float m = sum * (1.0f / VEC);
  float sq = 0.0f;
#pragma unroll
  for (int k = 0; k < 5; ++k) {
    const float dl = v[k] - m;
    sq += dl * dl;
  }
  sq = blockSum(sq, red);
  const float rstd = rsqrtf(sq * (1.0f / VEC) + 1e-5f);
  float* y = Y + (size_t)r * VEC;
#pragma unroll
  for (int k = 0; k < 5; ++k) stcc(y + tid + k * 256, (v[k] - m) * rstd);
}

// Fused layer-4 tail for batch b: scores4 + pv4 + LN + head, all in-block.
DEV void tail_task(int b, const Params& p) {
  __shared__ float qs[128], wvs[128], red[4], aws[256];
  __shared__ float xrow[1280], partial[256];
  __shared__ float h1s[32], h2s[12];
  const int tid = threadIdx.x;
  const int lp = p.lys[0];
  const float* X3 = p.buf0;

  if (tid < 128) {
    qs[tid] = ldcc(p.Qd + (size_t)(b * 256 + lp) * 128 + tid);
    wvs[tid] = p.wv[3][tid];
  }
  __syncthreads();
  const float* KTb = p.KT + (size_t)b * 32768 + tid;
  float s = 0.0f;
#pragma unroll 4
  for (int h = 0; h < 128; h += 4) {
    s += wvs[h + 0] * ftanh(qs[h + 0] + ldcc(KTb + (h + 0) * 256));
    s += wvs[h + 1] * ftanh(qs[h + 1] + ldcc(KTb + (h + 1) * 256));
    s += wvs[h + 2] * ftanh(qs[h + 2] + ldcc(KTb + (h + 2) * 256));
    s += wvs[h + 3] * ftanh(qs[h + 3] + ldcc(KTb + (h + 3) * 256));
  }
  const float mx = blockMax(s, red);
  const float e = __expf(s - mx);
  const float tot = blockSum(e, red);
  aws[tid] = e / tot;
  __syncthreads();

  // PV: 5 cols per thread (coalesced rows of X3[b]).
  const float* Xb = X3 + (size_t)b * SS * VEC;
  float v[5] = {};
#pragma unroll 2
  for (int j = 0; j < 256; ++j) {
    const float aw = aws[j];
    const float* xr = Xb + (size_t)j * VEC + tid;
#pragma unroll
    for (int k = 0; k < 5; ++k) v[k] = fmaf(aw, ldcc(xr + k * 256), v[k]);
  }
#pragma unroll
  for (int k = 0; k < 5; ++k)
    v[k] += ldcc(Xb + (size_t)lp * VEC + tid + k * 256);

  // LN over the 1280-wide attended row.
  float sum = (v[0] + v[1]) + (v[2] + v[3]) + v[4];
  sum = blockSum(sum, red);
  const float m = sum * (1.0f / VEC);
  float sq = 0.0f;
#pragma unroll
  for (int k = 0; k < 5; ++k) {
    const float dl = v[k] - m;
    sq += dl * dl;
  }
  sq = blockSum(sq, red);
  const float rstd = rsqrtf(sq * (1.0f / VEC) + 1e-5f);
#pragma unroll
  for (int k = 0; k < 5; ++k) xrow[tid + k * 256] = (v[k] - m) * rstd;
  __syncthreads();

  // Head: 1280 -> 32 (relu) -> 12 (relu) -> 2.
  {
    const int n = tid & 31, sl = tid >> 5;
    float pacc = 0.0f;
    for (int k = sl * 160; k < sl * 160 + 160; ++k)
      pacc = fmaf(xrow[k], p.hW1[(size_t)k * 32 + n], pacc);
    partial[tid] = pacc;
  }
  __syncthreads();
  if (tid < 32) {
    float t2 = 0.0f;
#pragma unroll
    for (int s2 = 0; s2 < 8; ++s2) t2 += partial[s2 * 32 + tid];
    h1s[tid] = fmaxf(t2 + p.hb1[tid], 0.0f);
  }
  __syncthreads();
  if (tid < 12) {
    float t2 = 0.0f;
#pragma unroll
    for (int k = 0; k < 32; ++k) t2 = fmaf(h1s[k], p.hW2[k * 12 + tid], t2);
    h2s[tid] = fmaxf(t2 + p.hb2[tid], 0.0f);
  }
  __syncthreads();
  if (tid < 2) {
    float t2 = 0.0f;
#pragma unroll
    for (int k = 0; k < 12; ++k) t2 = fmaf(h2s[k], p.hW3[k * 2 + tid], t2);
    p.out[b * 2 + tid] = t2 + p.hb3[tid];  // normal store: kernel-end release
  }
}

// ---------------------------------------------------------------------------
// The persistent kernel. 512 blocks x 256 threads; __launch_bounds__(256,2)
// -> 2 blocks/CU -> all 512 blocks co-resident (VGPR<=128 measured, LDS 36KB).
// ---------------------------------------------------------------------------
__global__ __launch_bounds__(256, 2) void mega_k(Params p) {
  const int bid = blockIdx.x;
  const float* Pin[4]  = {p.X, p.buf0, p.buf1, p.buf0};
  float*       Pout[3] = {p.buf0, p.buf1, p.buf0};
  unsigned ph = 0;

  for (int l = 0; l < 4; ++l) {
    const float* Xin = Pin[l];
    {  // QK projection: QKp[z] = Xin @ [Wq|Wk], K-slice z. 512 tasks.
      const int x = bid & 3, y = (bid >> 2) & 15, z = bid >> 6;
      gemm_task<1, false, false, false, true, false, false>(
          x * 64, y * 64, z, Xin, 0L, 0L,
          p.Wq[l], p.Wk[l], HID, 0L, HID, p.QKp, QK_PS,
          nullptr, nullptr, nullptr, 2 * HID, VEC, 160);
    }
    gsync(p.bar, ++ph);
    // Reduce partials -> dense Qd + transposed KT. 1024 rows / 512 blocks.
    qksum_task(bid, p.QKp, p.Qd, p.KT);
    qksum_task(bid + NBLK, p.QKp, p.Qd, p.KT);
    gsync(p.bar, ++ph);
    if (l == 3) break;
    // attn = softmax(wv . tanh(q_i + k_j)). 512 tasks.
    scores_task(bid, p.Qd, p.KT, p.wv[l], p.attn);
    gsync(p.bar, ++ph);
    // Yraw = attn @ Xin + Xin (batched). 320 tasks.
    if (bid < 320) {
      const int x = bid % 20, y = (bid / 20) & 3, zb = bid / 80;
      gemm_task<2, false, false, true, true, true, true>(
          x * 64, y * 64, zb, p.attn,
          (long)SS * SS, 0L, Xin, Xin, NSPLIT_NONE, (long)SS * VEC, VEC,
          p.Yraw, (long)SS * VEC, nullptr, nullptr, Xin, VEC, SS, 0);
    }
    gsync(p.bar, ++ph);
    // Yb = LN(Yraw). 1024 rows / 512 blocks.
    ln_task(bid, p.Yraw, p.Yb);
    ln_task(bid + NBLK, p.Yraw, p.Yb);
    gsync(p.bar, ++ph);
    // Hp[z] = Yb @ rW1, K-slice z. 256 tasks.
    if (bid < 256) {
      const int x = bid & 1, y = (bid >> 1) & 15, z = bid >> 5;
      gemm_task<1, false, false, false, true, false, false>(
          x * 64, y * 64, z, p.Yb, 0L, 0L,
          p.rW1[l], p.rW1[l], NSPLIT_NONE, 0L, HID, p.Hp, H_PS,
          nullptr, nullptr, nullptr, HID, VEC, 160);
    }
    gsync(p.bar, ++ph);
    // Xout = relu(sum(Hp)+b1) @ rW2 + b2 + Yb. 320 tasks.
    if (bid < 320) {
      const int x = bid % 20, y = bid / 20;
      gemm_task<0, true, true, true, true, false, true>(
          x * 64, y * 64, 0, p.Hp, 0L, H_PS,
          p.rW2[l], p.rW2[l], NSPLIT_NONE, 0L, VEC, Pout[l], 0L,
          p.rb1[l], p.rb2[l], p.Yb, VEC, HID, 0);
    }
    gsync(p.bar, ++ph);
  }
  // Layer-4 tail: one block per batch, fully fused.
  if (bid < BB) tail_task(bid, p);
}

__global__ void initbar_k(unsigned* __restrict__ bar) {
  const int tid = threadIdx.x;
  for (int i = tid; i < 512; i += 256)
    __hip_atomic_store(bar + i, 0u, __ATOMIC_RELAXED,
                       __HIP_MEMORY_SCOPE_AGENT);
}

// ---------------------------------------------------------------------------
extern "C" void kernel_launch(void* const* d_in, const int* in_sizes, int n_in,
                              void* d_out, int out_size, void* d_ws, size_t ws_size,
                              hipStream_t stream) {
  Params p;
  p.X   = (const float*)d_in[0];
  p.lys = (const int*)d_in[1];
  p.Wq[0] = (const float*)d_in[2];  p.Wk[0] = (const float*)d_in[3];  p.wv[0] = (const float*)d_in[4];
  p.Wq[1] = (const float*)d_in[5];  p.Wk[1] = (const float*)d_in[6];  p.wv[1] = (const float*)d_in[7];
  p.Wq[2] = (const float*)d_in[8];  p.Wk[2] = (const float*)d_in[9];  p.wv[2] = (const float*)d_in[10];
  p.Wq[3] = (const float*)d_in[11]; p.Wk[3] = (const float*)d_in[12]; p.wv[3] = (const float*)d_in[13];
  p.rW1[0] = (const float*)d_in[14]; p.rb1[0] = (const float*)d_in[15];
  p.rW2[0] = (const float*)d_in[16]; p.rb2[0] = (const float*)d_in[17];
  p.rW1[1] = (const float*)d_in[18]; p.rb1[1] = (const float*)d_in[19];
  p.rW2[1] = (const float*)d_in[20]; p.rb2[1] = (const float*)d_in[21];
  p.rW1[2] = (const float*)d_in[22]; p.rb1[2] = (const float*)d_in[23];
  p.rW2[2] = (const float*)d_in[24]; p.rb2[2] = (const float*)d_in[25];
  p.hW1 = (const float*)d_in[26]; p.hb1 = (const float*)d_in[27];
  p.hW2 = (const float*)d_in[28]; p.hb2 = (const float*)d_in[29];
  p.hW3 = (const float*)d_in[30]; p.hb3 = (const float*)d_in[31];
  p.out = (float*)d_out;

  // Workspace layout (floats), ~36 MB + barrier words.
  float* ws = (float*)d_ws;
  p.QKp  = ws;                               // NPART x 262144
  p.Qd   = p.QKp + (long)NPART * QK_PS;      // 1024*128
  p.KT   = p.Qd + 131072;                    // 4*128*256
  p.attn = p.KT + 131072;                    // 1024*256
  p.Yraw = p.attn + 262144;                  // 1024*1280
  p.Yb   = p.Yraw + 1310720;                 // 1024*1280
  p.Hp   = p.Yb + 1310720;                   // NPART x 131072
  p.buf0 = p.Hp + (long)NPART * H_PS;        // 1024*1280
  p.buf1 = p.buf0 + 1310720;                 // 1024*1280
  float* aw4 = p.buf1 + 1310720;             // (unused) 4*256
  float* A4  = aw4 + 1024;                   // (unused) 4*1280
  p.bar = (unsigned*)(A4 + 4 * VEC);         // 512 x u32 barrier state

  initbar_k<<<dim3(1), dim3(256), 0, stream>>>(p.bar);
  mega_k<<<dim3(NBLK), dim3(256), 0, stream>>>(p);
}

// Round 3
// 546.870 us; speedup vs baseline: 2.7306x; 1.0282x over previous
//
#include <hip/hip_runtime.h>

// AttentionBasedNN: persistent mega-kernel, round-7.
// VEC=1280, HID=128, B=4, S=256, fp32 (no fp32 MFMA on CDNA4 -> vector ALU).
//
// Round-6 post-mortem: fence-free barrier worked (~us each), but ALL
// intermediate traffic via sc0sc1 bypass loads ran at L3 latency with no
// caching/batching: 415 MB @ 900 GB/s effective, VALUBusy 25% -> ~350us of
// pure load latency.
//
// Round-7: keep bypass STORES (fire-and-forget to coherence point, vmcnt-
// tracked) + fence-free tree barrier. Make all intermediate LOADS normal
// cached float4 loads again (L1+L2 speed + reuse). Legal without any cache
// maintenance because every buffer is WRITE-ONCE (per-layer versioned
// instances, ~101 MB of workspace): bypass stores never dirty L1/L2;
// readers touch a buffer only after its producing barrier; prior-iteration
// copies are invalidated by the dispatch-start acquire. Hence no stale
// cache line can ever exist -> barriers need zero wbl2/inv.
// All buffer versions are >=4KB aligned (no 128B line spans two buffers).
// Arithmetic is bit-identical to rounds 4/5/6.

#define DEV __device__ __forceinline__

static constexpr int VEC = 1280;
static constexpr int HID = 128;
static constexpr int BB  = 4;
static constexpr int SS  = 256;
static constexpr int NPART = 8;           // split-K partials (QK and FC1)
static constexpr long QK_PS = 262144;     // QK partial stride (1024*256)
static constexpr long H_PS  = 131072;     // FC1 partial stride (1024*128)
static constexpr int NBLK  = 512;         // persistent grid: 2 blocks/CU
static constexpr int NSPLIT_NONE = 1 << 30;

struct Params {
  const float* X; const int* lys;
  const float* Wq[4]; const float* Wk[4]; const float* wv[4];
  const float* rW1[3]; const float* rb1[3]; const float* rW2[3]; const float* rb2[3];
  const float* hW1; const float* hb1; const float* hW2; const float* hb2;
  const float* hW3; const float* hb3;
  // Write-once versioned intermediates:
  float* QKp[4]; float* Qd[4]; float* KT[4];       // per attention layer
  float* attn[3]; float* Yraw[3]; float* Yb[3];    // per layer 0..2
  float* Hp[3]; float* Xout[3];                    // per layer 0..2
  float* out;
  unsigned* bar;   // [0..255] group counters (stride 32), [256] root, [288] gen
};

// ---- bypass stores for intermediates (agent-scope relaxed atomics) --------
// Compile to global_store with sc0 sc1: go straight to the coherence point,
// never dirty L1/L2. vmcnt-tracked, so __syncthreads drains them.
DEV void stcc(float* p, float v) {
  union { float f; unsigned u; } c; c.f = v;
  __hip_atomic_store((unsigned*)p, c.u, __ATOMIC_RELAXED,
                     __HIP_MEMORY_SCOPE_AGENT);
}
DEV void stcc2(float* p, float a, float b) {
  union { float2 f; unsigned long long u; } c; c.f = make_float2(a, b);
  __hip_atomic_store((unsigned long long*)p, c.u, __ATOMIC_RELAXED,
                     __HIP_MEMORY_SCOPE_AGENT);
}

DEV float ftanh(float x) {
  float e = __expf(2.0f * x);
  return 1.0f - __fdividef(2.0f, e + 1.0f);
}

DEV float waveSum(float v) {
#pragma unroll
  for (int off = 32; off > 0; off >>= 1) v += __shfl_xor(v, off, 64);
  return v;
}
DEV float waveMax(float v) {
#pragma unroll
  for (int off = 32; off > 0; off >>= 1) v = fmaxf(v, __shfl_xor(v, off, 64));
  return v;
}
// blockDim.x == 256 (4 waves) everywhere these are used.
DEV float blockSum(float v, float* red) {
  v = waveSum(v);
  int tid = threadIdx.x;
  if ((tid & 63) == 0) red[tid >> 6] = v;
  __syncthreads();
  float r = (red[0] + red[1]) + (red[2] + red[3]);
  __syncthreads();
  return r;
}
DEV float blockMax(float v, float* red) {
  v = waveMax(v);
  int tid = threadIdx.x;
  if ((tid & 63) == 0) red[tid >> 6] = v;
  __syncthreads();
  float r = fmaxf(fmaxf(red[0], red[1]), fmaxf(red[2], red[3]));
  __syncthreads();
  return r;
}

// Fence-free grid barrier (proven in round-6). Monotonic counters, no
// resets, no cache maintenance (see header comment for why none is needed).
DEV void gsync(unsigned* bar, unsigned target) {
  __syncthreads();  // drains this wave's vmcnt (stores at coherence point)
  if (threadIdx.x == 0) {
    asm volatile("s_waitcnt vmcnt(0)" ::: "memory");
    unsigned* grp  = bar + ((blockIdx.x >> 6) << 5);
    unsigned* root = bar + 256;
    unsigned* gen  = bar + 288;
    unsigned c = __hip_atomic_fetch_add(grp, 1u, __ATOMIC_RELAXED,
                                        __HIP_MEMORY_SCOPE_AGENT);
    if (c + 1u == target * 64u) {
      unsigned r = __hip_atomic_fetch_add(root, 1u, __ATOMIC_RELAXED,
                                          __HIP_MEMORY_SCOPE_AGENT);
      if (r + 1u == target * 8u) {
        __hip_atomic_store(gen, target, __ATOMIC_RELAXED,
                           __HIP_MEMORY_SCOPE_AGENT);
      }
    }
    while (__hip_atomic_load(gen, __ATOMIC_RELAXED,
                             __HIP_MEMORY_SCOPE_AGENT) < target)
      __builtin_amdgcn_s_sleep(2);
  }
  __syncthreads();
}

// ---------------------------------------------------------------------------
// fp32 GEMM task, 64x64 tile, BK=16, 256 threads, 4x4 microtile, register
// double-buffered staging. Identical math to rounds 4/5/6. Loads are normal
// cached float4 (write-once buffers make this safe); C-stores bypass.
// MODE==0: plain.  MODE==1: z = K-split slice (kChunk each), C += z*sCb.
// MODE==2: z = batch; A += z*sAb, B += z*sBb, C/res += z*sCb.
// AFUSE: A element = relu(sum of NPART partials (stride aPart) + aBias[k]).
// ---------------------------------------------------------------------------
template <int MODE, bool AFUSE, bool OBIAS, bool ORES>
DEV void gemm_task(int n0, int m0, int z,
                   const float* __restrict__ A, long sAb, long aPart,
                   const float* __restrict__ B0, const float* __restrict__ B1,
                   int nSplitB, long sBb, int ldB,
                   float* __restrict__ C, long sCb,
                   const float* __restrict__ aBias,
                   const float* __restrict__ oBias,
                   const float* __restrict__ res,
                   int N, int K, int kChunk) {
  __shared__ float As[16][68];  // [k][m]
  __shared__ float Bs[16][68];  // [k][n]

  const float* Ab = A + (MODE == 2 ? (long)z * sAb : 0L);
  float*       Cb = C + (MODE >= 1 ? (long)z * sCb : 0L);
  const float* resz = ORES ? (res + (MODE == 2 ? (long)z * sCb : 0L)) : nullptr;
  const float* Bsel;
  int nb;
  if (n0 < nSplitB) { Bsel = B0; nb = n0; } else { Bsel = B1; nb = n0 - nSplitB; }
  if (MODE == 2) Bsel += (long)z * sBb;

  const int kBeg = (MODE == 1) ? z * kChunk : 0;
  const int kEnd = (MODE == 1) ? kBeg + kChunk : K;

  const int tid = threadIdx.x;
  const int tx = tid & 15, ty = tid >> 4;
  const int ar = tid >> 2, ac = (tid & 3) << 2;   // A: row 0..63, k {0,4,8,12}
  const int br = tid >> 4, bc = (tid & 15) << 2;  // B: k-row 0..15, col 0..60

  auto loadA = [&](int kt) -> float4 {
    const size_t aoff = (size_t)(m0 + ar) * K + kt + ac;
    if (AFUSE) {
      float4 s = *(const float4*)(Ab + aoff);
#pragma unroll
      for (int p = 1; p < NPART; ++p) {
        const float4 t = *(const float4*)(Ab + (long)p * aPart + aoff);
        s.x += t.x; s.y += t.y; s.z += t.z; s.w += t.w;
      }
      const float4 bz = *(const float4*)(aBias + kt + ac);
      s.x = fmaxf(s.x + bz.x, 0.0f);
      s.y = fmaxf(s.y + bz.y, 0.0f);
      s.z = fmaxf(s.z + bz.z, 0.0f);
      s.w = fmaxf(s.w + bz.w, 0.0f);
      return s;
    }
    return *(const float4*)(Ab + aoff);
  };
  auto loadB = [&](int kt) -> float4 {
    return *(const float4*)(Bsel + (size_t)(kt + br) * ldB + nb + bc);
  };

  float acc[4][4] = {};
  float4 a4 = loadA(kBeg);
  float4 b4 = loadB(kBeg);

  for (int kt = kBeg; kt < kEnd; kt += 16) {
    __syncthreads();
    As[ac + 0][ar] = a4.x;
    As[ac + 1][ar] = a4.y;
    As[ac + 2][ar] = a4.z;
    As[ac + 3][ar] = a4.w;
    *(float4*)&Bs[br][bc] = b4;
    __syncthreads();
    if (kt + 16 < kEnd) {  // prefetch next tile under compute
      a4 = loadA(kt + 16);
      b4 = loadB(kt + 16);
    }
#pragma unroll
    for (int kk = 0; kk < 16; ++kk) {
      const float4 av = *(const float4*)&As[kk][ty << 2];
      const float4 bv = *(const float4*)&Bs[kk][tx << 2];
      const float a[4] = {av.x, av.y, av.z, av.w};
      const float b[4] = {bv.x, bv.y, bv.z, bv.w};
#pragma unroll
      for (int i = 0; i < 4; ++i)
#pragma unroll
        for (int j = 0; j < 4; ++j) acc[i][j] = fmaf(a[i], b[j], acc[i][j]);
    }
  }

#pragma unroll
  for (int i = 0; i < 4; ++i) {
    const int m = m0 + (ty << 2) + i;
    const int n = n0 + (tx << 2);
    float o[4] = {acc[i][0], acc[i][1], acc[i][2], acc[i][3]};
    if (OBIAS) {
#pragma unroll
      for (int j = 0; j < 4; ++j) o[j] += oBias[n + j];
    }
    if (ORES) {
      const float4 r4 = *(const float4*)(resz + (size_t)m * N + n);
      o[0] += r4.x; o[1] += r4.y; o[2] += r4.z; o[3] += r4.w;
    }
    stcc2(&Cb[(size_t)m * N + n], o[0], o[1]);
    stcc2(&Cb[(size_t)m * N + n + 2], o[2], o[3]);
  }
}

// Reduce NPART QK partials row r (cols 0..127=Q, 128..255=K) into Qd + KT.
DEV void qksum_task(int r, const float* __restrict__ QKp,
                    float* __restrict__ Qd, float* __restrict__ KT) {
  const int tid = threadIdx.x;
  const int b = r >> 8, j = r & 255;
  const size_t off = (size_t)r * 256 + tid;
  float v = 0.0f;
#pragma unroll
  for (int p = 0; p < NPART; ++p) v += QKp[(long)p * QK_PS + off];
  if (tid < 128) {
    stcc(Qd + (size_t)r * 128 + tid, v);
  } else {
    stcc(KT + (size_t)b * 32768 + (size_t)(tid - 128) * 256 + j, v);
  }
}

// Scores + softmax for 2 q-rows. t in [0,512): b = t>>7, i0 = (t&127)*2.
DEV void scores_task(int t, const float* __restrict__ Qd,
                     const float* __restrict__ KT,
                     const float* __restrict__ wv,
                     float* __restrict__ attn) {
  const int b = t >> 7, i0 = (t & 127) << 1, tid = threadIdx.x;
  __shared__ float qs[2][128], wvs[128], red[4];
  {
    const int rr = tid >> 7, h = tid & 127;
    qs[rr][h] = Qd[(size_t)(b * 256 + i0 + rr) * 128 + h];
  }
  if (tid < 128) wvs[tid] = wv[tid];
  __syncthreads();

  const float* KTb = KT + (size_t)b * 32768 + tid;
  float s0 = 0.0f, s1 = 0.0f;
#pragma unroll 4
  for (int h = 0; h < 128; h += 4) {
    const float k0 = KTb[(h + 0) * 256];
    const float k1 = KTb[(h + 1) * 256];
    const float k2 = KTb[(h + 2) * 256];
    const float k3 = KTb[(h + 3) * 256];
    const float w0 = wvs[h], w1 = wvs[h + 1], w2 = wvs[h + 2], w3 = wvs[h + 3];
    s0 += w0 * ftanh(qs[0][h] + k0) + w1 * ftanh(qs[0][h + 1] + k1) +
          w2 * ftanh(qs[0][h + 2] + k2) + w3 * ftanh(qs[0][h + 3] + k3);
    s1 += w0 * ftanh(qs[1][h] + k0) + w1 * ftanh(qs[1][h + 1] + k1) +
          w2 * ftanh(qs[1][h + 2] + k2) + w3 * ftanh(qs[1][h + 3] + k3);
  }
  {
    const float mx = blockMax(s0, red);
    const float e = __expf(s0 - mx);
    const float tot = blockSum(e, red);
    stcc(attn + (size_t)(b * 256 + i0) * 256 + tid, e / tot);
  }
  {
    const float mx = blockMax(s1, red);
    const float e = __expf(s1 - mx);
    const float tot = blockSum(e, red);
    stcc(attn + (size_t)(b * 256 + i0 + 1) * 256 + tid, e / tot);
  }
}

// LayerNorm of row r of A -> Y.
DEV void ln_task(int r, const float* __restrict__ A, float* __restrict__ Y) {
  __shared__ float red[4];
  const int tid = threadIdx.x;
  const float* a = A + (size_t)r * VEC;
  float v[5];
  float sum = 0.0f;
#pragma unroll
  for (int k = 0; k < 5; ++k) {
    v[k] = a[tid + k * 256];
    sum += v[k];
  }
  sum = blockSum(sum, red);
  const float m = sum * (1.0f / VEC);
  float sq = 0.0f;
#pragma unroll
  for (int k = 0; k < 5; ++k) {
    const float dl = v[k] - m;
    sq += dl * dl;
  }
  sq = blockSum(sq, red);
  const float rstd = rsqrtf(sq * (1.0f / VEC) + 1e-5f);
  float* y = Y + (size_t)r * VEC;
#pragma unroll
  for (int k = 0; k < 5; ++k) stcc(y + tid + k * 256, (v[k] - m) * rstd);
}

// Fused layer-4 tail for batch b: scores4 + pv4 + LN + head, all in-block.
DEV void tail_task(int b, const Params& p) {
  __shared__ float qs[128], wvs[128], red[4], aws[256];
  __shared__ float xrow[1280], partial[256];
  __shared__ float h1s[32], h2s[12];
  const int tid = threadIdx.x;
  const int lp = p.lys[0];
  const float* X3 = p.Xout[2];
  const float* Qd = p.Qd[3];
  const float* KT = p.KT[3];

  if (tid < 128) {
    qs[tid] = Qd[(size_t)(b * 256 + lp) * 128 + tid];
    wvs[tid] = p.wv[3][tid];
  }
  __syncthreads();
  const float* KTb = KT + (size_t)b * 32768 + tid;
  float s = 0.0f;
#pragma unroll 4
  for (int h = 0; h < 128; h += 4) {
    s += wvs[h + 0] * ftanh(qs[h + 0] + KTb[(h + 0) * 256]);
    s += wvs[h + 1] * ftanh(qs[h + 1] + KTb[(h + 1) * 256]);
    s += wvs[h + 2] * ftanh(qs[h + 2] + KTb[(h + 2) * 256]);
    s += wvs[h + 3] * ftanh(qs[h + 3] + KTb[(h + 3) * 256]);
  }
  const float mx = blockMax(s, red);
  const float e = __expf(s - mx);
  const float tot = blockSum(e, red);
  aws[tid] = e / tot;
  __syncthreads();

  // PV: 5 cols per thread (coalesced rows of X3[b]).
  const float* Xb = X3 + (size_t)b * SS * VEC;
  float v[5] = {};
#pragma unroll 2
  for (int j = 0; j < 256; ++j) {
    const float aw = aws[j];
    const float* xr = Xb + (size_t)j * VEC + tid;
#pragma unroll
    for (int k = 0; k < 5; ++k) v[k] = fmaf(aw, xr[k * 256], v[k]);
  }
#pragma unroll
  for (int k = 0; k < 5; ++k) v[k] += Xb[(size_t)lp * VEC + tid + k * 256];

  // LN over the 1280-wide attended row.
  float sum = (v[0] + v[1]) + (v[2] + v[3]) + v[4];
  sum = blockSum(sum, red);
  const float m = sum * (1.0f / VEC);
  float sq = 0.0f;
#pragma unroll
  for (int k = 0; k < 5; ++k) {
    const float dl = v[k] - m;
    sq += dl * dl;
  }
  sq = blockSum(sq, red);
  const float rstd = rsqrtf(sq * (1.0f / VEC) + 1e-5f);
#pragma unroll
  for (int k = 0; k < 5; ++k) xrow[tid + k * 256] = (v[k] - m) * rstd;
  __syncthreads();

  // Head: 1280 -> 32 (relu) -> 12 (relu) -> 2.
  {
    const int n = tid & 31, sl = tid >> 5;
    float pacc = 0.0f;
    for (int k = sl * 160; k < sl * 160 + 160; ++k)
      pacc = fmaf(xrow[k], p.hW1[(size_t)k * 32 + n], pacc);
    partial[tid] = pacc;
  }
  __syncthreads();
  if (tid < 32) {
    float t2 = 0.0f;
#pragma unroll
    for (int s2 = 0; s2 < 8; ++s2) t2 += partial[s2 * 32 + tid];
    h1s[tid] = fmaxf(t2 + p.hb1[tid], 0.0f);
  }
  __syncthreads();
  if (tid < 12) {
    float t2 = 0.0f;
#pragma unroll
    for (int k = 0; k < 32; ++k) t2 = fmaf(h1s[k], p.hW2[k * 12 + tid], t2);
    h2s[tid] = fmaxf(t2 + p.hb2[tid], 0.0f);
  }
  __syncthreads();
  if (tid < 2) {
    float t2 = 0.0f;
#pragma unroll
    for (int k = 0; k < 12; ++k) t2 = fmaf(h2s[k], p.hW3[k * 2 + tid], t2);
    p.out[b * 2 + tid] = t2 + p.hb3[tid];  // normal store: kernel-end release
  }
}

// ---------------------------------------------------------------------------
// The persistent kernel. 512 blocks x 256 threads; __launch_bounds__(256,2)
// -> 2 blocks/CU -> all 512 blocks co-resident (VGPR<=128, LDS 36KB).
// ---------------------------------------------------------------------------
__global__ __launch_bounds__(256, 2) void mega_k(Params p) {
  const int bid = blockIdx.x;
  unsigned ph = 0;

  for (int l = 0; l < 4; ++l) {
    const float* Xin = (l == 0) ? p.X : p.Xout[l - 1];
    {  // QK projection: QKp[l][z] = Xin @ [Wq|Wk], K-slice z. 512 tasks.
      const int x = bid & 3, y = (bid >> 2) & 15, z = bid >> 6;
      gemm_task<1, false, false, false>(x * 64, y * 64, z, Xin, 0L, 0L,
          p.Wq[l], p.Wk[l], HID, 0L, HID, p.QKp[l], QK_PS,
          nullptr, nullptr, nullptr, 2 * HID, VEC, 160);
    }
    gsync(p.bar, ++ph);
    // Reduce partials -> dense Qd + transposed KT. 1024 rows / 512 blocks.
    qksum_task(bid, p.QKp[l], p.Qd[l], p.KT[l]);
    qksum_task(bid + NBLK, p.QKp[l], p.Qd[l], p.KT[l]);
    gsync(p.bar, ++ph);
    if (l == 3) break;
    // attn = softmax(wv . tanh(q_i + k_j)). 512 tasks.
    scores_task(bid, p.Qd[l], p.KT[l], p.wv[l], p.attn[l]);
    gsync(p.bar, ++ph);
    // Yraw = attn @ Xin + Xin (batched). 320 tasks.
    if (bid < 320) {
      const int x = bid % 20, y = (bid / 20) & 3, zb = bid / 80;
      gemm_task<2, false, false, true>(x * 64, y * 64, zb, p.attn[l],
          (long)SS * SS, 0L, Xin, Xin, NSPLIT_NONE, (long)SS * VEC, VEC,
          p.Yraw[l], (long)SS * VEC, nullptr, nullptr, Xin, VEC, SS, 0);
    }
    gsync(p.bar, ++ph);
    // Yb = LN(Yraw). 1024 rows / 512 blocks.
    ln_task(bid, p.Yraw[l], p.Yb[l]);
    ln_task(bid + NBLK, p.Yraw[l], p.Yb[l]);
    gsync(p.bar, ++ph);
    // Hp[z] = Yb @ rW1, K-slice z. 256 tasks.
    if (bid < 256) {
      const int x = bid & 1, y = (bid >> 1) & 15, z = bid >> 5;
      gemm_task<1, false, false, false>(x * 64, y * 64, z, p.Yb[l], 0L, 0L,
          p.rW1[l], p.rW1[l], NSPLIT_NONE, 0L, HID, p.Hp[l], H_PS,
          nullptr, nullptr, nullptr, HID, VEC, 160);
    }
    gsync(p.bar, ++ph);
    // Xout = relu(sum(Hp)+b1) @ rW2 + b2 + Yb. 320 tasks.
    if (bid < 320) {
      const int x = bid % 20, y = bid / 20;
      gemm_task<0, true, true, true>(x * 64, y * 64, 0, p.Hp[l], 0L, H_PS,
          p.rW2[l], p.rW2[l], NSPLIT_NONE, 0L, VEC, p.Xout[l], 0L,
          p.rb1[l], p.rb2[l], p.Yb[l], VEC, HID, 0);
    }
    gsync(p.bar, ++ph);
  }
  // Layer-4 tail: one block per batch, fully fused.
  if (bid < BB) tail_task(bid, p);
}

__global__ void initbar_k(unsigned* __restrict__ bar) {
  const int tid = threadIdx.x;
  for (int i = tid; i < 512; i += 256)
    __hip_atomic_store(bar + i, 0u, __ATOMIC_RELAXED,
                       __HIP_MEMORY_SCOPE_AGENT);
}

// ---------------------------------------------------------------------------
extern "C" void kernel_launch(void* const* d_in, const int* in_sizes, int n_in,
                              void* d_out, int out_size, void* d_ws, size_t ws_size,
                              hipStream_t stream) {
  Params p;
  p.X   = (const float*)d_in[0];
  p.lys = (const int*)d_in[1];
  p.Wq[0] = (const float*)d_in[2];  p.Wk[0] = (const float*)d_in[3];  p.wv[0] = (const float*)d_in[4];
  p.Wq[1] = (const float*)d_in[5];  p.Wk[1] = (const float*)d_in[6];  p.wv[1] = (const float*)d_in[7];
  p.Wq[2] = (const float*)d_in[8];  p.Wk[2] = (const float*)d_in[9];  p.wv[2] = (const float*)d_in[10];
  p.Wq[3] = (const float*)d_in[11]; p.Wk[3] = (const float*)d_in[12]; p.wv[3] = (const float*)d_in[13];
  p.rW1[0] = (const float*)d_in[14]; p.rb1[0] = (const float*)d_in[15];
  p.rW2[0] = (const float*)d_in[16]; p.rb2[0] = (const float*)d_in[17];
  p.rW1[1] = (const float*)d_in[18]; p.rb1[1] = (const float*)d_in[19];
  p.rW2[1] = (const float*)d_in[20]; p.rb2[1] = (const float*)d_in[21];
  p.rW1[2] = (const float*)d_in[22]; p.rb1[2] = (const float*)d_in[23];
  p.rW2[2] = (const float*)d_in[24]; p.rb2[2] = (const float*)d_in[25];
  p.hW1 = (const float*)d_in[26]; p.hb1 = (const float*)d_in[27];
  p.hW2 = (const float*)d_in[28]; p.hb2 = (const float*)d_in[29];
  p.hW3 = (const float*)d_in[30]; p.hb3 = (const float*)d_in[31];
  p.out = (float*)d_out;

  // Write-once versioned workspace (floats), ~101 MB total. All sizes are
  // multiples of 4KB so no cache line spans two buffers.
  float* w = (float*)d_ws;
  for (int l = 0; l < 4; ++l) { p.QKp[l] = w; w += (long)NPART * QK_PS; }  // 4 x 8MB
  for (int l = 0; l < 4; ++l) { p.Qd[l]  = w; w += 131072; }               // 4 x 0.5MB
  for (int l = 0; l < 4; ++l) { p.KT[l]  = w; w += 131072; }               // 4 x 0.5MB
  for (int l = 0; l < 3; ++l) { p.attn[l] = w; w += 262144; }              // 3 x 1MB
  for (int l = 0; l < 3; ++l) { p.Yraw[l] = w; w += 1310720; }             // 3 x 5MB
  for (int l = 0; l < 3; ++l) { p.Yb[l]   = w; w += 1310720; }             // 3 x 5MB
  for (int l = 0; l < 3; ++l) { p.Hp[l]   = w; w += (long)NPART * H_PS; }  // 3 x 4MB
  for (int l = 0; l < 3; ++l) { p.Xout[l] = w; w += 1310720; }             // 3 x 5MB
  p.bar = (unsigned*)w;                                                    // 512 u32

  initbar_k<<<dim3(1), dim3(256), 0, stream>>>(p.bar);
  mega_k<<<dim3(NBLK), dim3(256), 0, stream>>>(p);
}

// Round 5
// 523.864 us; speedup vs baseline: 2.8505x; 1.0439x over previous
//
#include <hip/hip_runtime.h>

// AttentionBasedNN: persistent mega-kernel, round-9.
// VEC=1280, HID=128, B=4, S=256, fp32 (no fp32 MFMA on CDNA4 -> vector ALU).
//
// Coherence scheme (proven rounds 6/7): intermediates are WRITE-ONCE
// versioned buffers; stores bypass L1/L2 (sc0 sc1 -> coherence point),
// loads normal cached; grid barrier = fence-free monotonic tree counters.
//
// Round-8 post-mortem: container hang. Suspect: exact-fit residency
// (launch_bounds(256,4) limit == 4/CU request, zero slack) -> barrier
// deadlock on dispatch imbalance. Rule: request < limit (slack >= 1.5x).
//
// Round-9 = round-7 skeleton (512 blocks x 256 thr, launch_bounds(256,2),
// static LDS ~41KB -> limit 3/CU vs request 2/CU) + two surgical changes:
//  (1) 2-tile-deep register ping-pong prefetch in non-AFUSE GEMMs
//      (load window ~1024cy >> L3 latency; FMA order unchanged).
//  (2) 16B bypass stores (global_store_dwordx4 sc0 sc1) for GEMM epilogues
//      and LN output (LDS-staged, value-identical) -- fabric write granule
//      measured ~16B, so this halves WRITE_SIZE.

#define DEV __device__ __forceinline__

static constexpr int VEC = 1280;
static constexpr int HID = 128;
static constexpr int BB  = 4;
static constexpr int SS  = 256;
static constexpr int NPART = 8;           // split-K partials (QK and FC1)
static constexpr long QK_PS = 262144;     // QK partial stride (1024*256)
static constexpr long H_PS  = 131072;     // FC1 partial stride (1024*128)
static constexpr int NBLK  = 512;         // persistent grid: 2 blocks/CU
static constexpr int NSPLIT_NONE = 1 << 30;

typedef float f32x4 __attribute__((ext_vector_type(4)));

struct Params {
  const float* X; const int* lys;
  const float* Wq[4]; const float* Wk[4]; const float* wv[4];
  const float* rW1[3]; const float* rb1[3]; const float* rW2[3]; const float* rb2[3];
  const float* hW1; const float* hb1; const float* hW2; const float* hb2;
  const float* hW3; const float* hb3;
  float* QKp[4]; float* Qd[4]; float* KT[4];       // per attention layer
  float* attn[3]; float* Yraw[3]; float* Yb[3];    // per layer 0..2
  float* Hp[3]; float* Xout[3];                    // per layer 0..2
  float* out;
  unsigned* bar;   // [0..255] group counters (stride 32), [256] root, [288] gen
};

// ---- bypass stores (agent-scope, straight to coherence point) -------------
DEV void stcc(float* p, float v) {
  union { float f; unsigned u; } c; c.f = v;
  __hip_atomic_store((unsigned*)p, c.u, __ATOMIC_RELAXED,
                     __HIP_MEMORY_SCOPE_AGENT);
}
DEV void stcc4(float* p, float x, float y, float z, float w) {
  f32x4 v; v[0] = x; v[1] = y; v[2] = z; v[3] = w;
  asm volatile("global_store_dwordx4 %0, %1, off sc0 sc1"
               :: "v"(p), "v"(v) : "memory");
}

DEV float ftanh(float x) {
  float e = __expf(2.0f * x);
  return 1.0f - __fdividef(2.0f, e + 1.0f);
}

DEV float waveSum(float v) {
#pragma unroll
  for (int off = 32; off > 0; off >>= 1) v += __shfl_xor(v, off, 64);
  return v;
}
DEV float waveMax(float v) {
#pragma unroll
  for (int off = 32; off > 0; off >>= 1) v = fmaxf(v, __shfl_xor(v, off, 64));
  return v;
}
// blockDim.x == 256 (4 waves) everywhere these are used.
DEV float blockSum(float v, float* red) {
  v = waveSum(v);
  int tid = threadIdx.x;
  if ((tid & 63) == 0) red[tid >> 6] = v;
  __syncthreads();
  float r = (red[0] + red[1]) + (red[2] + red[3]);
  __syncthreads();
  return r;
}
DEV float blockMax(float v, float* red) {
  v = waveMax(v);
  int tid = threadIdx.x;
  if ((tid & 63) == 0) red[tid >> 6] = v;
  __syncthreads();
  float r = fmaxf(fmaxf(red[0], red[1]), fmaxf(red[2], red[3]));
  __syncthreads();
  return r;
}

// Fence-free grid barrier (proven rounds 6/7). 8 groups of 64 blocks.
DEV void gsync(unsigned* bar, unsigned target) {
  __syncthreads();  // each wave drains its own vmcnt before s_barrier
  if (threadIdx.x == 0) {
    asm volatile("s_waitcnt vmcnt(0)" ::: "memory");
    unsigned* grp  = bar + ((blockIdx.x >> 6) << 5);
    unsigned* root = bar + 256;
    unsigned* gen  = bar + 288;
    unsigned c = __hip_atomic_fetch_add(grp, 1u, __ATOMIC_RELAXED,
                                        __HIP_MEMORY_SCOPE_AGENT);
    if (c + 1u == target * 64u) {
      unsigned r = __hip_atomic_fetch_add(root, 1u, __ATOMIC_RELAXED,
                                          __HIP_MEMORY_SCOPE_AGENT);
      if (r + 1u == target * 8u) {
        __hip_atomic_store(gen, target, __ATOMIC_RELAXED,
                           __HIP_MEMORY_SCOPE_AGENT);
      }
    }
    while (__hip_atomic_load(gen, __ATOMIC_RELAXED,
                             __HIP_MEMORY_SCOPE_AGENT) < target)
      __builtin_amdgcn_s_sleep(2);
  }
  __syncthreads();
}

// ---------------------------------------------------------------------------
// fp32 GEMM task, 64x64 tile, BK=16, 256 threads, 4x4 microtile.
// Non-AFUSE: 2-tile-deep ping-pong register prefetch (k-tile order and FMA
// order identical to round-7). AFUSE: depth-1 (8 partial streams already in
// flight). Loads cached (write-once buffers); C-stores bypass 16B.
// MODE==0: plain.  MODE==1: z = K-split slice (kChunk each), C += z*sCb.
// MODE==2: z = batch; A += z*sAb, B += z*sBb, C/res += z*sCb.
// ---------------------------------------------------------------------------
template <int MODE, bool AFUSE, bool OBIAS, bool ORES>
DEV void gemm_task(int n0, int m0, int z,
                   const float* __restrict__ A, long sAb, long aPart,
                   const float* __restrict__ B0, const float* __restrict__ B1,
                   int nSplitB, long sBb, int ldB,
                   float* __restrict__ C, long sCb,
                   const float* __restrict__ aBias,
                   const float* __restrict__ oBias,
                   const float* __restrict__ res,
                   int N, int K, int kChunk) {
  __shared__ float As[16][68];  // [k][m]
  __shared__ float Bs[16][68];  // [k][n]

  const float* Ab = A + (MODE == 2 ? (long)z * sAb : 0L);
  float*       Cb = C + (MODE >= 1 ? (long)z * sCb : 0L);
  const float* resz = ORES ? (res + (MODE == 2 ? (long)z * sCb : 0L)) : nullptr;
  const float* Bsel;
  int nb;
  if (n0 < nSplitB) { Bsel = B0; nb = n0; } else { Bsel = B1; nb = n0 - nSplitB; }
  if (MODE == 2) Bsel += (long)z * sBb;

  const int kBeg = (MODE == 1) ? z * kChunk : 0;
  const int kEnd = (MODE == 1) ? kBeg + kChunk : K;

  const int tid = threadIdx.x;
  const int tx = tid & 15, ty = tid >> 4;
  const int ar = tid >> 2, ac = (tid & 3) << 2;   // A: row 0..63, k {0,4,8,12}
  const int br = tid >> 4, bc = (tid & 15) << 2;  // B: k-row 0..15, col 0..60

  auto loadA = [&](int kt) -> float4 {
    const size_t aoff = (size_t)(m0 + ar) * K + kt + ac;
    if (AFUSE) {
      float4 s = *(const float4*)(Ab + aoff);
#pragma unroll
      for (int p = 1; p < NPART; ++p) {
        const float4 t = *(const float4*)(Ab + (long)p * aPart + aoff);
        s.x += t.x; s.y += t.y; s.z += t.z; s.w += t.w;
      }
      const float4 bz = *(const float4*)(aBias + kt + ac);
      s.x = fmaxf(s.x + bz.x, 0.0f);
      s.y = fmaxf(s.y + bz.y, 0.0f);
      s.z = fmaxf(s.z + bz.z, 0.0f);
      s.w = fmaxf(s.w + bz.w, 0.0f);
      return s;
    }
    return *(const float4*)(Ab + aoff);
  };
  auto loadB = [&](int kt) -> float4 {
    return *(const float4*)(Bsel + (size_t)(kt + br) * ldB + nb + bc);
  };
  auto stAB = [&](const float4& a4, const float4& b4) {
    As[ac + 0][ar] = a4.x;
    As[ac + 1][ar] = a4.y;
    As[ac + 2][ar] = a4.z;
    As[ac + 3][ar] = a4.w;
    *(float4*)&Bs[br][bc] = b4;
  };

  float acc[4][4] = {};
  auto domath = [&]() {
#pragma unroll
    for (int kk = 0; kk < 16; ++kk) {
      const float4 av = *(const float4*)&As[kk][ty << 2];
      const float4 bv = *(const float4*)&Bs[kk][tx << 2];
      const float a[4] = {av.x, av.y, av.z, av.w};
      const float b[4] = {bv.x, bv.y, bv.z, bv.w};
#pragma unroll
      for (int i = 0; i < 4; ++i)
#pragma unroll
        for (int j = 0; j < 4; ++j) acc[i][j] = fmaf(a[i], b[j], acc[i][j]);
    }
  };

  if constexpr (!AFUSE) {
    // 2-deep ping-pong: slot A = even tiles, slot B = odd tiles; each slot
    // reloaded 2 tiles ahead -> ~2 FMA blocks of load window.
    float4 aA = loadA(kBeg), bA = loadB(kBeg);
    float4 aB = aA, bB = bA;  // init only; unused unless >=2 tiles
    if (kBeg + 16 < kEnd) { aB = loadA(kBeg + 16); bB = loadB(kBeg + 16); }
    for (int kt = kBeg; kt < kEnd; kt += 32) {
      __syncthreads();
      stAB(aA, bA);
      __syncthreads();
      if (kt + 32 < kEnd) { aA = loadA(kt + 32); bA = loadB(kt + 32); }
      domath();
      if (kt + 16 < kEnd) {
        __syncthreads();
        stAB(aB, bB);
        __syncthreads();
        if (kt + 48 < kEnd) { aB = loadA(kt + 48); bB = loadB(kt + 48); }
        domath();
      }
    }
  } else {
    float4 a4 = loadA(kBeg), b4 = loadB(kBeg);
    for (int kt = kBeg; kt < kEnd; kt += 16) {
      __syncthreads();
      stAB(a4, b4);
      __syncthreads();
      if (kt + 16 < kEnd) { a4 = loadA(kt + 16); b4 = loadB(kt + 16); }
      domath();
    }
  }

#pragma unroll
  for (int i = 0; i < 4; ++i) {
    const int m = m0 + (ty << 2) + i;
    const int n = n0 + (tx << 2);
    float o[4] = {acc[i][0], acc[i][1], acc[i][2], acc[i][3]};
    if (OBIAS) {
#pragma unroll
      for (int j = 0; j < 4; ++j) o[j] += oBias[n + j];
    }
    if (ORES) {
      const float4 r4 = *(const float4*)(resz + (size_t)m * N + n);
      o[0] += r4.x; o[1] += r4.y; o[2] += r4.z; o[3] += r4.w;
    }
    stcc4(&Cb[(size_t)m * N + n], o[0], o[1], o[2], o[3]);
  }
}

// Reduce NPART QK partials row r (cols 0..127=Q, 128..255=K) into Qd + KT.
DEV void qksum_task(int r, const float* __restrict__ QKp,
                    float* __restrict__ Qd, float* __restrict__ KT) {
  const int tid = threadIdx.x;
  const int b = r >> 8, j = r & 255;
  const size_t off = (size_t)r * 256 + tid;
  float v = 0.0f;
#pragma unroll
  for (int p = 0; p < NPART; ++p) v += QKp[(long)p * QK_PS + off];
  if (tid < 128) {
    stcc(Qd + (size_t)r * 128 + tid, v);
  } else {
    stcc(KT + (size_t)b * 32768 + (size_t)(tid - 128) * 256 + j, v);
  }
}

// Scores + softmax for 2 q-rows. t in [0,512): b = t>>7, i0 = (t&127)*2.
DEV void scores_task(int t, const float* __restrict__ Qd,
                     const float* __restrict__ KT,
                     const float* __restrict__ wv,
                     float* __restrict__ attn) {
  const int b = t >> 7, i0 = (t & 127) << 1, tid = threadIdx.x;
  __shared__ float qs[2][128], wvs[128], red[4];
  {
    const int rr = tid >> 7, h = tid & 127;
    qs[rr][h] = Qd[(size_t)(b * 256 + i0 + rr) * 128 + h];
  }
  if (tid < 128) wvs[tid] = wv[tid];
  __syncthreads();

  const float* KTb = KT + (size_t)b * 32768 + tid;
  float s0 = 0.0f, s1 = 0.0f;
#pragma unroll 4
  for (int h = 0; h < 128; h += 4) {
    const float k0 = KTb[(h + 0) * 256];
    const float k1 = KTb[(h + 1) * 256];
    const float k2 = KTb[(h + 2) * 256];
    const float k3 = KTb[(h + 3) * 256];
    const float w0 = wvs[h], w1 = wvs[h + 1], w2 = wvs[h + 2], w3 = wvs[h + 3];
    s0 += w0 * ftanh(qs[0][h] + k0) + w1 * ftanh(qs[0][h + 1] + k1) +
          w2 * ftanh(qs[0][h + 2] + k2) + w3 * ftanh(qs[0][h + 3] + k3);
    s1 += w0 * ftanh(qs[1][h] + k0) + w1 * ftanh(qs[1][h + 1] + k1) +
          w2 * ftanh(qs[1][h + 2] + k2) + w3 * ftanh(qs[1][h + 3] + k3);
  }
  {
    const float mx = blockMax(s0, red);
    const float e = __expf(s0 - mx);
    const float tot = blockSum(e, red);
    stcc(attn + (size_t)(b * 256 + i0) * 256 + tid, e / tot);
  }
  {
    const float mx = blockMax(s1, red);
    const float e = __expf(s1 - mx);
    const float tot = blockSum(e, red);
    stcc(attn + (size_t)(b * 256 + i0 + 1) * 256 + tid, e / tot);
  }
}

// LayerNorm of row r of A -> Y. Values identical to round-7; output is
// staged in LDS and written as 16B bypass stores (320 float4 chunks).
DEV void ln_task(int r, const float* __restrict__ A, float* __restrict__ Y) {
  __shared__ float red[4];
  __shared__ float xbuf[1280];
  const int tid = threadIdx.x;
  const float* a = A + (size_t)r * VEC;
  float v[5];
  float sum = 0.0f;
#pragma unroll
  for (int k = 0; k < 5; ++k) {
    v[k] = a[tid + k * 256];
    sum += v[k];
  }
  sum = blockSum(sum, red);
  const float m = sum * (1.0f / VEC);
  float sq = 0.0f;
#pragma unroll
  for (int k = 0; k < 5; ++k) {
    const float dl = v[k] - m;
    sq += dl * dl;
  }
  sq = blockSum(sq, red);
  const float rstd = rsqrtf(sq * (1.0f / VEC) + 1e-5f);
#pragma unroll
  for (int k = 0; k < 5; ++k) xbuf[tid + k * 256] = (v[k] - m) * rstd;
  __syncthreads();
  float* y = Y + (size_t)r * VEC;
  {
    const float* x = xbuf + (tid << 2);
    stcc4(y + (tid << 2), x[0], x[1], x[2], x[3]);
  }
  if (tid < 64) {
    const float* x = xbuf + 1024 + (tid << 2);
    stcc4(y + 1024 + (tid << 2), x[0], x[1], x[2], x[3]);
  }
  __syncthreads();  // xbuf reused by second ln_task call
}

// Fused layer-4 tail for batch b: scores4 + pv4 + LN + head, all in-block.
DEV void tail_task(int b, const Params& p) {
  __shared__ float qs[128], wvs[128], red[4], aws[256];
  __shared__ float xrow[1280], partial[256];
  __shared__ float h1s[32], h2s[12];
  const int tid = threadIdx.x;
  const int lp = p.lys[0];
  const float* X3 = p.Xout[2];
  const float* Qd = p.Qd[3];
  const float* KT = p.KT[3];

  if (tid < 128) {
    qs[tid] = Qd[(size_t)(b * 256 + lp) * 128 + tid];
    wvs[tid] = p.wv[3][tid];
  }
  __syncthreads();
  const float* KTb = KT + (size_t)b * 32768 + tid;
  float s = 0.0f;
#pragma unroll 4
  for (int h = 0; h < 128; h += 4) {
    s += wvs[h + 0] * ftanh(qs[h + 0] + KTb[(h + 0) * 256]);
    s += wvs[h + 1] * ftanh(qs[h + 1] + KTb[(h + 1) * 256]);
    s += wvs[h + 2] * ftanh(qs[h + 2] + KTb[(h + 2) * 256]);
    s += wvs[h + 3] * ftanh(qs[h + 3] + KTb[(h + 3) * 256]);
  }
  const float mx = blockMax(s, red);
  const float e = __expf(s - mx);
  const float tot = blockSum(e, red);
  aws[tid] = e / tot;
  __syncthreads();

  // PV: 5 cols per thread (coalesced rows of X3[b]).
  const float* Xb = X3 + (size_t)b * SS * VEC;
  float v[5] = {};
#pragma unroll 2
  for (int j = 0; j < 256; ++j) {
    const float aw = aws[j];
    const float* xr = Xb + (size_t)j * VEC + tid;
#pragma unroll
    for (int k = 0; k < 5; ++k) v[k] = fmaf(aw, xr[k * 256], v[k]);
  }
#pragma unroll
  for (int k = 0; k < 5; ++k) v[k] += Xb[(size_t)lp * VEC + tid + k * 256];

  // LN over the 1280-wide attended row.
  float sum = (v[0] + v[1]) + (v[2] + v[3]) + v[4];
  sum = blockSum(sum, red);
  const float m = sum * (1.0f / VEC);
  float sq = 0.0f;
#pragma unroll
  for (int k = 0; k < 5; ++k) {
    const float dl = v[k] - m;
    sq += dl * dl;
  }
  sq = blockSum(sq, red);
  const float rstd = rsqrtf(sq * (1.0f / VEC) + 1e-5f);
#pragma unroll
  for (int k = 0; k < 5; ++k) xrow[tid + k * 256] = (v[k] - m) * rstd;
  __syncthreads();

  // Head: 1280 -> 32 (relu) -> 12 (relu) -> 2.
  {
    const int n = tid & 31, sl = tid >> 5;
    float pacc = 0.0f;
    for (int k = sl * 160; k < sl * 160 + 160; ++k)
      pacc = fmaf(xrow[k], p.hW1[(size_t)k * 32 + n], pacc);
    partial[tid] = pacc;
  }
  __syncthreads();
  if (tid < 32) {
    float t2 = 0.0f;
#pragma unroll
    for (int s2 = 0; s2 < 8; ++s2) t2 += partial[s2 * 32 + tid];
    h1s[tid] = fmaxf(t2 + p.hb1[tid], 0.0f);
  }
  __syncthreads();
  if (tid < 12) {
    float t2 = 0.0f;
#pragma unroll
    for (int k = 0; k < 32; ++k) t2 = fmaf(h1s[k], p.hW2[k * 12 + tid], t2);
    h2s[tid] = fmaxf(t2 + p.hb2[tid], 0.0f);
  }
  __syncthreads();
  if (tid < 2) {
    float t2 = 0.0f;
#pragma unroll
    for (int k = 0; k < 12; ++k) t2 = fmaf(h2s[k], p.hW3[k * 2 + tid], t2);
    p.out[b * 2 + tid] = t2 + p.hb3[tid];  // normal store: kernel-end release
  }
}

// ---------------------------------------------------------------------------
// The persistent kernel. 512 blocks x 256 threads; __launch_bounds__(256,2)
// (VGPR cap 256). LDS ~41KB -> occupancy limit 3 blocks/CU > 2 requested.
// ---------------------------------------------------------------------------
__global__ __launch_bounds__(256, 2) void mega_k(Params p) {
  const int bid = blockIdx.x;
  unsigned ph = 0;

  for (int l = 0; l < 4; ++l) {
    const float* Xin = (l == 0) ? p.X : p.Xout[l - 1];
    {  // QK projection: QKp[l][z] = Xin @ [Wq|Wk], K-slice z. 512 tasks.
      const int x = bid & 3, y = (bid >> 2) & 15, z = bid >> 6;
      gemm_task<1, false, false, false>(x * 64, y * 64, z, Xin, 0L, 0L,
          p.Wq[l], p.Wk[l], HID, 0L, HID, p.QKp[l], QK_PS,
          nullptr, nullptr, nullptr, 2 * HID, VEC, 160);
    }
    gsync(p.bar, ++ph);
    // Reduce partials -> dense Qd + transposed KT. 1024 rows / 512 blocks.
    qksum_task(bid, p.QKp[l], p.Qd[l], p.KT[l]);
    qksum_task(bid + NBLK, p.QKp[l], p.Qd[l], p.KT[l]);
    gsync(p.bar, ++ph);
    if (l == 3) break;
    // attn = softmax(wv . tanh(q_i + k_j)). 512 tasks.
    scores_task(bid, p.Qd[l], p.KT[l], p.wv[l], p.attn[l]);
    gsync(p.bar, ++ph);
    // Yraw = attn @ Xin + Xin (batched). 320 tasks.
    if (bid < 320) {
      const int x = bid % 20, y = (bid / 20) & 3, zb = bid / 80;
      gemm_task<2, false, false, true>(x * 64, y * 64, zb, p.attn[l],
          (long)SS * SS, 0L, Xin, Xin, NSPLIT_NONE, (long)SS * VEC, VEC,
          p.Yraw[l], (long)SS * VEC, nullptr, nullptr, Xin, VEC, SS, 0);
    }
    gsync(p.bar, ++ph);
    // Yb = LN(Yraw). 1024 rows / 512 blocks.
    ln_task(bid, p.Yraw[l], p.Yb[l]);
    ln_task(bid + NBLK, p.Yraw[l], p.Yb[l]);
    gsync(p.bar, ++ph);
    // Hp[z] = Yb @ rW1, K-slice z. 256 tasks.
    if (bid < 256) {
      const int x = bid & 1, y = (bid >> 1) & 15, z = bid >> 5;
      gemm_task<1, false, false, false>(x * 64, y * 64, z, p.Yb[l], 0L, 0L,
          p.rW1[l], p.rW1[l], NSPLIT_NONE, 0L, HID, p.Hp[l], H_PS,
          nullptr, nullptr, nullptr, HID, VEC, 160);
    }
    gsync(p.bar, ++ph);
    // Xout = relu(sum(Hp)+b1) @ rW2 + b2 + Yb. 320 tasks.
    if (bid < 320) {
      const int x = bid % 20, y = bid / 20;
      gemm_task<0, true, true, true>(x * 64, y * 64, 0, p.Hp[l], 0L, H_PS,
          p.rW2[l], p.rW2[l], NSPLIT_NONE, 0L, VEC, p.Xout[l], 0L,
          p.rb1[l], p.rb2[l], p.Yb[l], VEC, HID, 0);
    }
    gsync(p.bar, ++ph);
  }
  // Layer-4 tail: one block per batch, fully fused.
  if (bid < BB) tail_task(bid, p);
}

__global__ void initbar_k(unsigned* __restrict__ bar) {
  const int tid = threadIdx.x;
  for (int i = tid; i < 512; i += 256)
    __hip_atomic_store(bar + i, 0u, __ATOMIC_RELAXED,
                       __HIP_MEMORY_SCOPE_AGENT);
}

// ---------------------------------------------------------------------------
extern "C" void kernel_launch(void* const* d_in, const int* in_sizes, int n_in,
                              void* d_out, int out_size, void* d_ws, size_t ws_size,
                              hipStream_t stream) {
  Params p;
  p.X   = (const float*)d_in[0];
  p.lys = (const int*)d_in[1];
  p.Wq[0] = (const float*)d_in[2];  p.Wk[0] = (const float*)d_in[3];  p.wv[0] = (const float*)d_in[4];
  p.Wq[1] = (const float*)d_in[5];  p.Wk[1] = (const float*)d_in[6];  p.wv[1] = (const float*)d_in[7];
  p.Wq[2] = (const float*)d_in[8];  p.Wk[2] = (const float*)d_in[9];  p.wv[2] = (const float*)d_in[10];
  p.Wq[3] = (const float*)d_in[11]; p.Wk[3] = (const float*)d_in[12]; p.wv[3] = (const float*)d_in[13];
  p.rW1[0] = (const float*)d_in[14]; p.rb1[0] = (const float*)d_in[15];
  p.rW2[0] = (const float*)d_in[16]; p.rb2[0] = (const float*)d_in[17];
  p.rW1[1] = (const float*)d_in[18]; p.rb1[1] = (const float*)d_in[19];
  p.rW2[1] = (const float*)d_in[20]; p.rb2[1] = (const float*)d_in[21];
  p.rW1[2] = (const float*)d_in[22]; p.rb1[2] = (const float*)d_in[23];
  p.rW2[2] = (const float*)d_in[24]; p.rb2[2] = (const float*)d_in[25];
  p.hW1 = (const float*)d_in[26]; p.hb1 = (const float*)d_in[27];
  p.hW2 = (const float*)d_in[28]; p.hb2 = (const float*)d_in[29];
  p.hW3 = (const float*)d_in[30]; p.hb3 = (const float*)d_in[31];
  p.out = (float*)d_out;

  // Write-once versioned workspace (floats), ~101 MB total (4KB-aligned
  // buffers; no cache line spans two versions).
  float* w = (float*)d_ws;
  for (int l = 0; l < 4; ++l) { p.QKp[l] = w; w += (long)NPART * QK_PS; }  // 4 x 8MB
  for (int l = 0; l < 4; ++l) { p.Qd[l]  = w; w += 131072; }               // 4 x 0.5MB
  for (int l = 0; l < 4; ++l) { p.KT[l]  = w; w += 131072; }               // 4 x 0.5MB
  for (int l = 0; l < 3; ++l) { p.attn[l] = w; w += 262144; }              // 3 x 1MB
  for (int l = 0; l < 3; ++l) { p.Yraw[l] = w; w += 1310720; }             // 3 x 5MB
  for (int l = 0; l < 3; ++l) { p.Yb[l]   = w; w += 1310720; }             // 3 x 5MB
  for (int l = 0; l < 3; ++l) { p.Hp[l]   = w; w += (long)NPART * H_PS; }  // 3 x 4MB
  for (int l = 0; l < 3; ++l) { p.Xout[l] = w; w += 1310720; }             // 3 x 5MB
  p.bar = (unsigned*)w;                                                    // 512 u32

  initbar_k<<<dim3(1), dim3(256), 0, stream>>>(p.bar);
  mega_k<<<dim3(NBLK), dim3(256), 0, stream>>>(p);
}